// Round 13
// baseline (778.690 us; speedup 1.0000x reference)
//
#include <hip/hip_runtime.h>
#include <hip/hip_fp16.h>

#define NN 100000
#define NE 1000000
#define F_INF 128
#define HID 64
#define NLAY 6
#define NCLS 10
#define NGRAPH 64
#define PART_SZ 12500   // NN/8 — contiguous node range per XCD partition
#define SCAT_BLKS (((NE + 2047) / 2048) * 8)   // 489*8 = 3912
#define GEMM_GRID ((NN + 63) / 64)             // 1563

__device__ __forceinline__ float4 h4f(ushort4 u) {
    __half2 lo = *reinterpret_cast<__half2*>(&u);
    __half2 hi = *reinterpret_cast<__half2*>(reinterpret_cast<unsigned short*>(&u) + 2);
    float2 a = __half22float2(lo);
    float2 b = __half22float2(hi);
    return make_float4(a.x, a.y, b.x, b.y);
}

__device__ __forceinline__ ushort4 f4h(float4 v) {
    __half2 lo = __floats2half2_rn(v.x, v.y);
    __half2 hi = __floats2half2_rn(v.z, v.w);
    ushort4 u;
    *reinterpret_cast<__half2*>(&u) = lo;
    *reinterpret_cast<__half2*>(reinterpret_cast<unsigned short*>(&u) + 2) = hi;
    return u;
}

__device__ __forceinline__ unsigned short f2h(float v) {
    __half h = __float2half_rn(v);
    return *reinterpret_cast<unsigned short*>(&h);
}

__device__ __forceinline__ float h2f(unsigned short u) {
    __half h = *reinterpret_cast<__half*>(&u);
    return __half2float(h);
}

// ================= CSR build =================
__global__ void k_hist(const int* __restrict__ dst, int* __restrict__ counts, int e) {
    int i0 = blockIdx.x * 1024 + threadIdx.x;
    #pragma unroll
    for (int k = 0; k < 4; k++) {
        int i = i0 + k * 256;
        if (i < e) atomicAdd(&counts[dst[i]], 1);
    }
}

__global__ void k_blocksum(const int* __restrict__ counts, int* __restrict__ bsum, int n) {
    int i = blockIdx.x * 256 + threadIdx.x;
    int v = (i < n) ? counts[i] : 0;
    #pragma unroll
    for (int off = 32; off >= 1; off >>= 1) v += __shfl_down(v, off);
    __shared__ int ws[4];
    if ((threadIdx.x & 63) == 0) ws[threadIdx.x >> 6] = v;
    __syncthreads();
    if (threadIdx.x == 0) bsum[blockIdx.x] = ws[0] + ws[1] + ws[2] + ws[3];
}

__global__ void k_scanbsum(int* __restrict__ bsum, int nb) {   // 1 block, 512 thr
    __shared__ int sh[512];
    int t = threadIdx.x;
    int v = (t < nb) ? bsum[t] : 0;
    sh[t] = v; __syncthreads();
    for (int off = 1; off < 512; off <<= 1) {
        int x = (t >= off) ? sh[t - off] : 0;
        __syncthreads();
        sh[t] += x; __syncthreads();
    }
    if (t < nb) bsum[t] = sh[t] - v;   // exclusive
}

__global__ void k_scanwrite(const int* __restrict__ counts, const int* __restrict__ bsumx,
                            int* __restrict__ rowptr, int* __restrict__ wptr,
                            float* __restrict__ disq, int n, int e) {
    __shared__ int sh[256];
    int t = threadIdx.x;
    int i = blockIdx.x * 256 + t;
    int v = (i < n) ? counts[i] : 0;
    sh[t] = v; __syncthreads();
    for (int off = 1; off < 256; off <<= 1) {
        int x = (t >= off) ? sh[t - off] : 0;
        __syncthreads();
        sh[t] += x; __syncthreads();
    }
    int excl = sh[t] - v + bsumx[blockIdx.x];
    if (i < n) {
        rowptr[i] = excl;
        wptr[i]   = excl;
        disq[i]   = rsqrtf((float)(v + 1));   // +1 self-loop
    }
    if (i == 0) rowptr[n] = e;
}

// ============ fused: XCD-partitioned scatter + layer-0 GEMM (17KB LDS, K-chunk=32) ============
__global__ __launch_bounds__(256) void k_scatter_gemm0(
    const int* __restrict__ src, const int* __restrict__ dst,
    int* __restrict__ wptr, int* __restrict__ csr, int e,
    const float* __restrict__ x, const float* __restrict__ W0,
    const float* __restrict__ disq, unsigned short* __restrict__ C16, int n)
{
    __shared__ float Ws[32 * 64];
    __shared__ float As[64 * 36];

    if (blockIdx.x < SCAT_BLKS) {
        int part = blockIdx.x & 7;
        int i0 = (blockIdx.x >> 3) * 2048 + threadIdx.x;
        #pragma unroll
        for (int k = 0; k < 8; k++) {
            int i = i0 + k * 256;
            if (i < e) {
                int d = dst[i];
                if (d / PART_SZ == part) {
                    int pos = atomicAdd(&wptr[d], 1);
                    csr[pos] = src[i];
                }
            }
        }
        return;
    }

    const int tid  = threadIdx.x;
    const int col4 = (tid & 15) * 4;
    const int rowq = tid >> 4;
    const int base = (blockIdx.x - SCAT_BLKS) * 64;
    const int ar   = tid >> 3;
    const int ac4  = (tid & 7) * 4;

    float4 wreg[2], areg[2];
    #pragma unroll
    for (int i = 0; i < 2; i++)
        wreg[i] = *(const float4*)(W0 + (size_t)(i * 256 + tid) * 4);
    #pragma unroll
    for (int rr = 0; rr < 2; rr++) {
        int row = base + ar + rr * 32;
        areg[rr] = make_float4(0.f, 0.f, 0.f, 0.f);
        if (row < n) areg[rr] = *(const float4*)(x + (size_t)row * F_INF + ac4);
    }
    #pragma unroll
    for (int i = 0; i < 2; i++)
        *(float4*)(Ws + (size_t)(i * 256 + tid) * 4) = wreg[i];
    #pragma unroll
    for (int rr = 0; rr < 2; rr++)
        *(float4*)(As + (size_t)(ar + rr * 32) * 36 + ac4) = areg[rr];
    __syncthreads();

    float4 acc[4];
    #pragma unroll
    for (int r = 0; r < 4; r++) acc[r] = make_float4(0.f, 0.f, 0.f, 0.f);

    for (int k0 = 0; k0 < F_INF; k0 += 32) {
        const bool more = (k0 + 32) < F_INF;
        if (more) {
            #pragma unroll
            for (int i = 0; i < 2; i++)
                wreg[i] = *(const float4*)(W0 + (size_t)(k0 + 32) * 64 + (i * 256 + tid) * 4);
            #pragma unroll
            for (int rr = 0; rr < 2; rr++) {
                int row = base + ar + rr * 32;
                areg[rr] = make_float4(0.f, 0.f, 0.f, 0.f);
                if (row < n) areg[rr] = *(const float4*)(x + (size_t)row * F_INF + k0 + 32 + ac4);
            }
        }
        #pragma unroll 8
        for (int k = 0; k < 32; k++) {
            float4 w = *(const float4*)(Ws + k * 64 + col4);
            float a0 = As[(rowq * 4 + 0) * 36 + k];
            float a1 = As[(rowq * 4 + 1) * 36 + k];
            float a2 = As[(rowq * 4 + 2) * 36 + k];
            float a3 = As[(rowq * 4 + 3) * 36 + k];
            acc[0].x = fmaf(a0, w.x, acc[0].x); acc[0].y = fmaf(a0, w.y, acc[0].y);
            acc[0].z = fmaf(a0, w.z, acc[0].z); acc[0].w = fmaf(a0, w.w, acc[0].w);
            acc[1].x = fmaf(a1, w.x, acc[1].x); acc[1].y = fmaf(a1, w.y, acc[1].y);
            acc[1].z = fmaf(a1, w.z, acc[1].z); acc[1].w = fmaf(a1, w.w, acc[1].w);
            acc[2].x = fmaf(a2, w.x, acc[2].x); acc[2].y = fmaf(a2, w.y, acc[2].y);
            acc[2].z = fmaf(a2, w.z, acc[2].z); acc[2].w = fmaf(a2, w.w, acc[2].w);
            acc[3].x = fmaf(a3, w.x, acc[3].x); acc[3].y = fmaf(a3, w.y, acc[3].y);
            acc[3].z = fmaf(a3, w.z, acc[3].z); acc[3].w = fmaf(a3, w.w, acc[3].w);
        }
        __syncthreads();
        if (more) {
            #pragma unroll
            for (int i = 0; i < 2; i++)
                *(float4*)(Ws + (size_t)(i * 256 + tid) * 4) = wreg[i];
            #pragma unroll
            for (int rr = 0; rr < 2; rr++)
                *(float4*)(As + (size_t)(ar + rr * 32) * 36 + ac4) = areg[rr];
            __syncthreads();
        }
    }

    #pragma unroll
    for (int r = 0; r < 4; r++) {
        int row = base + rowq * 4 + r;
        if (row < n) {
            float s = disq[row];
            float4 o;
            o.x = acc[r].x * s; o.y = acc[r].y * s;
            o.z = acc[r].z * s; o.w = acc[r].w * s;
            ((ushort4*)C16)[(size_t)row * 16 + (tid & 15)] = f4h(o);
        }
    }
}

// ============ fused gather + per-wave next-layer GEMM + jk fold (layers 0-4) ============
// 1 wave per node. After the reduce ALL lanes hold the full h-row (chunk lane&15,
// replicated x4). Lane l then computes output column l of h@Wn and h@jkw via
// 16 broadcast steps. Zero LDS; W reads are coalesced and L1-hot.
__global__ __launch_bounds__(256) void k_gather_fused(
    const int* __restrict__ rowptr, const int* __restrict__ csr,
    const unsigned short* __restrict__ hW16in, const float* __restrict__ disq,
    const float* __restrict__ bias,
    const float* __restrict__ Wn,      // next-layer weight [64][64]
    const float* __restrict__ jkw,     // this h's JK block [64][64]
    unsigned short* __restrict__ hW16out,
    unsigned short* __restrict__ jkacc16,
    int jk_mode, int n)
{
    const ushort4* hW4 = (const ushort4*)hW16in;
    int wid  = (blockIdx.x * 256 + threadIdx.x) >> 6;
    if (wid >= n) return;
    int lane = threadIdx.x & 63;
    int fb = lane & 15;
    int es = lane >> 4;
    int j  = rowptr[wid];
    int r1 = rowptr[wid + 1];
    float4 v  = make_float4(0.f, 0.f, 0.f, 0.f);
    float4 v2 = make_float4(0.f, 0.f, 0.f, 0.f);
    if (es == 0) v = h4f(hW4[(size_t)wid * 16 + fb]);    // self-loop
    while (j < r1) {
        int cnt = min(r1 - j, 64);
        int idx = (lane < cnt) ? csr[j + lane] : 0;
        for (int jj = 0; jj < cnt; jj += 16) {
            int i0 = jj + es, i1 = jj + 4 + es, i2 = jj + 8 + es, i3 = jj + 12 + es;
            int s0 = __shfl(idx, i0 & 63);
            int s1 = __shfl(idx, i1 & 63);
            int s2 = __shfl(idx, i2 & 63);
            int s3 = __shfl(idx, i3 & 63);
            float4 t0 = h4f(hW4[(size_t)s0 * 16 + fb]);
            float4 t1 = h4f(hW4[(size_t)s1 * 16 + fb]);
            float4 t2 = h4f(hW4[(size_t)s2 * 16 + fb]);
            float4 t3 = h4f(hW4[(size_t)s3 * 16 + fb]);
            if (i0 < cnt) { v.x  += t0.x; v.y  += t0.y; v.z  += t0.z; v.w  += t0.w; }
            if (i1 < cnt) { v2.x += t1.x; v2.y += t1.y; v2.z += t1.z; v2.w += t1.w; }
            if (i2 < cnt) { v.x  += t2.x; v.y  += t2.y; v.z  += t2.z; v.w  += t2.w; }
            if (i3 < cnt) { v2.x += t3.x; v2.y += t3.y; v2.z += t3.z; v2.w += t3.w; }
        }
        j += cnt;
    }
    v.x += v2.x; v.y += v2.y; v.z += v2.z; v.w += v2.w;
    v.x += __shfl_xor(v.x, 16); v.y += __shfl_xor(v.y, 16);
    v.z += __shfl_xor(v.z, 16); v.w += __shfl_xor(v.w, 16);
    v.x += __shfl_xor(v.x, 32); v.y += __shfl_xor(v.y, 32);
    v.z += __shfl_xor(v.z, 32); v.w += __shfl_xor(v.w, 32);

    // h (relu'd, chunk fb) on ALL lanes
    float s = disq[wid];
    float4 b = ((const float4*)bias)[fb];
    float4 h;
    h.x = fmaxf(fmaf(s, v.x, b.x), 0.f);
    h.y = fmaxf(fmaf(s, v.y, b.y), 0.f);
    h.z = fmaxf(fmaf(s, v.z, b.z), 0.f);
    h.w = fmaxf(fmaf(s, v.w, b.w), 0.f);

    // per-wave dual GEMV: lane owns output column `lane`
    float accw = 0.f, accj = 0.f;
    #pragma unroll
    for (int c = 0; c < 16; c++) {
        float h0 = __shfl(h.x, c);
        float h1 = __shfl(h.y, c);
        float h2 = __shfl(h.z, c);
        float h3 = __shfl(h.w, c);
        const float* wp = Wn  + (size_t)c * 256 + lane;   // rows 4c..4c+3, col lane
        const float* jp = jkw + (size_t)c * 256 + lane;
        accw = fmaf(h0, wp[0],   accw);
        accw = fmaf(h1, wp[64],  accw);
        accw = fmaf(h2, wp[128], accw);
        accw = fmaf(h3, wp[192], accw);
        accj = fmaf(h0, jp[0],   accj);
        accj = fmaf(h1, jp[64],  accj);
        accj = fmaf(h2, jp[128], accj);
        accj = fmaf(h3, jp[192], accj);
    }

    size_t oidx = (size_t)wid * 64 + lane;
    hW16out[oidx] = f2h(accw * s);          // pre-scaled by disq for next gather
    if (jk_mode == 1) {
        jkacc16[oidx] = f2h(accj);
    } else {
        jkacc16[oidx] = f2h(h2f(jkacc16[oidx]) + accj);
    }
}

// ============ plain gather (layer 5): writes h16 for jkfin ============
__global__ __launch_bounds__(256) void k_gather(
    const int* __restrict__ rowptr, const int* __restrict__ csr,
    const unsigned short* __restrict__ hW16, const float* __restrict__ disq,
    const float* __restrict__ bias, unsigned short* __restrict__ hout16, int n)
{
    const ushort4* hW4 = (const ushort4*)hW16;
    int wid  = (blockIdx.x * 256 + threadIdx.x) >> 6;
    if (wid >= n) return;
    int lane = threadIdx.x & 63;
    int fb = lane & 15;
    int es = lane >> 4;
    int j  = rowptr[wid];
    int r1 = rowptr[wid + 1];
    float4 v  = make_float4(0.f, 0.f, 0.f, 0.f);
    float4 v2 = make_float4(0.f, 0.f, 0.f, 0.f);
    if (es == 0) v = h4f(hW4[(size_t)wid * 16 + fb]);
    while (j < r1) {
        int cnt = min(r1 - j, 64);
        int idx = (lane < cnt) ? csr[j + lane] : 0;
        for (int jj = 0; jj < cnt; jj += 16) {
            int i0 = jj + es, i1 = jj + 4 + es, i2 = jj + 8 + es, i3 = jj + 12 + es;
            int s0 = __shfl(idx, i0 & 63);
            int s1 = __shfl(idx, i1 & 63);
            int s2 = __shfl(idx, i2 & 63);
            int s3 = __shfl(idx, i3 & 63);
            float4 t0 = h4f(hW4[(size_t)s0 * 16 + fb]);
            float4 t1 = h4f(hW4[(size_t)s1 * 16 + fb]);
            float4 t2 = h4f(hW4[(size_t)s2 * 16 + fb]);
            float4 t3 = h4f(hW4[(size_t)s3 * 16 + fb]);
            if (i0 < cnt) { v.x  += t0.x; v.y  += t0.y; v.z  += t0.z; v.w  += t0.w; }
            if (i1 < cnt) { v2.x += t1.x; v2.y += t1.y; v2.z += t1.z; v2.w += t1.w; }
            if (i2 < cnt) { v.x  += t2.x; v.y  += t2.y; v.z  += t2.z; v.w  += t2.w; }
            if (i3 < cnt) { v2.x += t3.x; v2.y += t3.y; v2.z += t3.z; v2.w += t3.w; }
        }
        j += cnt;
    }
    v.x += v2.x; v.y += v2.y; v.z += v2.z; v.w += v2.w;
    v.x += __shfl_xor(v.x, 16); v.y += __shfl_xor(v.y, 16);
    v.z += __shfl_xor(v.z, 16); v.w += __shfl_xor(v.w, 16);
    v.x += __shfl_xor(v.x, 32); v.y += __shfl_xor(v.y, 32);
    v.z += __shfl_xor(v.z, 32); v.w += __shfl_xor(v.w, 32);
    if (es == 0) {
        float s = disq[wid];
        float4 b = ((const float4*)bias)[fb];
        float4 o;
        o.x = fmaxf(fmaf(s, v.x, b.x), 0.f);
        o.y = fmaxf(fmaf(s, v.y, b.y), 0.f);
        o.z = fmaxf(fmaf(s, v.z, b.z), 0.f);
        o.w = fmaxf(fmaf(s, v.w, b.w), 0.f);
        ((ushort4*)hout16)[(size_t)wid * 16 + fb] = f4h(o);
    }
}

// ============ final: t = relu(h@jkW5 + jkacc + jkb); pool by batch ============
__global__ __launch_bounds__(256) void k_jkfin_pool(
    const unsigned short* __restrict__ A16,
    const float* __restrict__ W,
    const unsigned short* __restrict__ jkacc16,
    const float* __restrict__ bias,
    const int* __restrict__ batch,
    float* __restrict__ pooled,
    int n)
{
    __shared__ float Ws[64 * 64];
    __shared__ float As[64 * 68];
    const int tid  = threadIdx.x;
    const int col4 = (tid & 15) * 4;
    const int rowq = tid >> 4;
    const int base = blockIdx.x * 64;

    #pragma unroll
    for (int i = 0; i < 4; i++) {
        float4 v = *(const float4*)(W + (size_t)(i * 256 + tid) * 4);
        *(float4*)(Ws + (size_t)(i * 256 + tid) * 4) = v;
    }
    {
        const ushort4* Ah = (const ushort4*)A16;
        #pragma unroll
        for (int rr = 0; rr < 4; rr++) {
            int row = base + rowq + rr * 16;
            float4 v = make_float4(0.f, 0.f, 0.f, 0.f);
            if (row < n) v = h4f(Ah[(size_t)row * 16 + (tid & 15)]);
            *(float4*)(As + (size_t)(rowq + rr * 16) * 68 + col4) = v;
        }
    }
    __syncthreads();

    float4 acc[4];
    #pragma unroll
    for (int r = 0; r < 4; r++) acc[r] = make_float4(0.f, 0.f, 0.f, 0.f);
    #pragma unroll 8
    for (int k = 0; k < 64; k++) {
        float4 w = *(const float4*)(Ws + k * 64 + col4);
        float a0 = As[(rowq * 4 + 0) * 68 + k];
        float a1 = As[(rowq * 4 + 1) * 68 + k];
        float a2 = As[(rowq * 4 + 2) * 68 + k];
        float a3 = As[(rowq * 4 + 3) * 68 + k];
        acc[0].x = fmaf(a0, w.x, acc[0].x); acc[0].y = fmaf(a0, w.y, acc[0].y);
        acc[0].z = fmaf(a0, w.z, acc[0].z); acc[0].w = fmaf(a0, w.w, acc[0].w);
        acc[1].x = fmaf(a1, w.x, acc[1].x); acc[1].y = fmaf(a1, w.y, acc[1].y);
        acc[1].z = fmaf(a1, w.z, acc[1].z); acc[1].w = fmaf(a1, w.w, acc[1].w);
        acc[2].x = fmaf(a2, w.x, acc[2].x); acc[2].y = fmaf(a2, w.y, acc[2].y);
        acc[2].z = fmaf(a2, w.z, acc[2].z); acc[2].w = fmaf(a2, w.w, acc[2].w);
        acc[3].x = fmaf(a3, w.x, acc[3].x); acc[3].y = fmaf(a3, w.y, acc[3].y);
        acc[3].z = fmaf(a3, w.z, acc[3].z); acc[3].w = fmaf(a3, w.w, acc[3].w);
    }
    __syncthreads();

    float* slab = Ws;
    #pragma unroll
    for (int i = tid; i < 4096; i += 256) slab[i] = 0.f;
    __syncthreads();

    float4 bb = *(const float4*)(bias + col4);
    int curg = -1;
    float4 s4 = make_float4(0.f, 0.f, 0.f, 0.f);
    #pragma unroll
    for (int r = 0; r < 4; r++) {
        int row = base + rowq * 4 + r;
        if (row < n) {
            float4 p = h4f(((const ushort4*)jkacc16)[(size_t)row * 16 + (tid & 15)]);
            float4 vv;
            vv.x = fmaxf(acc[r].x + p.x + bb.x, 0.f);
            vv.y = fmaxf(acc[r].y + p.y + bb.y, 0.f);
            vv.z = fmaxf(acc[r].z + p.z + bb.z, 0.f);
            vv.w = fmaxf(acc[r].w + p.w + bb.w, 0.f);
            int g = batch[row];
            if (g != curg) {
                if (curg >= 0) {
                    atomicAdd(&slab[curg * 64 + col4 + 0], s4.x);
                    atomicAdd(&slab[curg * 64 + col4 + 1], s4.y);
                    atomicAdd(&slab[curg * 64 + col4 + 2], s4.z);
                    atomicAdd(&slab[curg * 64 + col4 + 3], s4.w);
                }
                curg = g; s4 = vv;
            } else {
                s4.x += vv.x; s4.y += vv.y; s4.z += vv.z; s4.w += vv.w;
            }
        }
    }
    if (curg >= 0) {
        atomicAdd(&slab[curg * 64 + col4 + 0], s4.x);
        atomicAdd(&slab[curg * 64 + col4 + 1], s4.y);
        atomicAdd(&slab[curg * 64 + col4 + 2], s4.z);
        atomicAdd(&slab[curg * 64 + col4 + 3], s4.w);
    }
    __syncthreads();

    int g0 = batch[base];
    int g1 = batch[(base + 63 < n) ? (base + 63) : (n - 1)];
    int cnt = (g1 - g0 + 1) * 64;
    for (int i = tid; i < cnt; i += 256) {
        int g = g0 + (i >> 6);
        int c = i & 63;
        float v = slab[g * 64 + c];
        if (v != 0.f) atomicAdd(&pooled[g * 64 + c], v);
    }
}

// ============ head ============
__global__ __launch_bounds__(64) void k_head(
    const float* __restrict__ pooled,
    const float* __restrict__ W1, const float* __restrict__ b1,
    const float* __restrict__ W2, const float* __restrict__ b2,
    float* __restrict__ out)
{
    __shared__ float p[64];
    __shared__ float h1[64];
    __shared__ float lg[16];
    const int g = blockIdx.x;
    const int t = threadIdx.x;

    p[t] = pooled[g * 64 + t];
    __syncthreads();

    float acc = b1[t];
    #pragma unroll 8
    for (int k = 0; k < 64; k++) acc = fmaf(p[k], W1[k * 64 + t], acc);
    h1[t] = fmaxf(acc, 0.f);
    __syncthreads();

    if (t < NCLS) {
        float a = b2[t];
        #pragma unroll 8
        for (int j = 0; j < 64; j++) a = fmaf(h1[j], W2[j * NCLS + t], a);
        lg[t] = a;
    }
    __syncthreads();

    if (t == 0) {
        float mx = lg[0];
        #pragma unroll
        for (int c = 1; c < NCLS; c++) mx = fmaxf(mx, lg[c]);
        float ssum = 0.f;
        float e[NCLS];
        #pragma unroll
        for (int c = 0; c < NCLS; c++) { e[c] = __expf(lg[c] - mx); ssum += e[c]; }
        float inv = 1.0f / ssum;
        #pragma unroll
        for (int c = 0; c < NCLS; c++) out[g * NCLS + c] = e[c] * inv;
    }
}

extern "C" void kernel_launch(void* const* d_in, const int* in_sizes, int n_in,
                              void* d_out, int out_size, void* d_ws, size_t ws_size,
                              hipStream_t stream) {
    (void)in_sizes; (void)n_in; (void)out_size; (void)ws_size;
    const float* x     = (const float*)d_in[0];
    const int*   ei    = (const int*)d_in[1];
    const int*   batch = (const int*)d_in[2];
    const float* W0    = (const float*)d_in[3];
    const float* b0    = (const float*)d_in[4];
    const float* Wh    = (const float*)d_in[5];
    const float* bh    = (const float*)d_in[6];
    const float* jkW   = (const float*)d_in[7];   // [384][64] = 6 stacked [64][64]
    const float* jkb   = (const float*)d_in[8];
    const float* W1    = (const float*)d_in[9];
    const float* b1    = (const float*)d_in[10];
    const float* W2    = (const float*)d_in[11];
    const float* b2    = (const float*)d_in[12];

    const int* src = ei;
    const int* dst = ei + NE;

    float*          fws     = (float*)d_ws;
    float*          disq    = fws;                                   // 100352 f
    unsigned short* hWbA    = (unsigned short*)(disq + 100352);      // NN*64 fp16
    unsigned short* hWbB    = hWbA + (size_t)NN * 64;                // NN*64 fp16
    unsigned short* h16     = hWbB + (size_t)NN * 64;                // NN*64 fp16
    unsigned short* jkacc16 = h16 + (size_t)NN * 64;                 // NN*64 fp16
    float*          pooled  = (float*)(jkacc16 + (size_t)NN * 64);   // 4096 f
    int*            counts  = (int*)(pooled + 4096);
    int*            rowptr  = counts + 100352;
    int*            wptr    = rowptr + 100352;
    int*            bsum    = wptr + 100352;
    int*            csr     = bsum + 512;

    const int NB_N = (NN + 255) / 256;

    hipMemsetAsync(counts, 0, (size_t)NN * sizeof(int), stream);
    k_hist<<<(NE + 1023) / 1024, 256, 0, stream>>>(dst, counts, NE);
    k_blocksum<<<NB_N, 256, 0, stream>>>(counts, bsum, NN);
    k_scanbsum<<<1, 512, 0, stream>>>(bsum, NB_N);
    k_scanwrite<<<NB_N, 256, 0, stream>>>(counts, bsum, rowptr, wptr, disq, NN, NE);

    // fused scatter + layer-0 GEMM -> hWbA
    k_scatter_gemm0<<<SCAT_BLKS + GEMM_GRID, 256, 0, stream>>>(
        src, dst, wptr, csr, NE, x, W0, disq, hWbA, NN);

    const int gather_grid = (NN + 3) / 4;    // 25000
    // layers 0..4: fused gather + next-layer GEMM + jk fold; ping-pong A<->B
    unsigned short* bufs[2] = { hWbA, hWbB };
    for (int l = 0; l < 5; l++) {
        const float* gb  = (l == 0) ? b0 : (bh + (size_t)(l - 1) * 64);
        const float* Wn  = Wh + (size_t)l * 64 * 64;        // weight for layer l+1
        const float* jw  = jkW + (size_t)l * 64 * 64;       // jk block of h_l
        int          jkm = (l == 0) ? 1 : 2;
        k_gather_fused<<<gather_grid, 256, 0, stream>>>(
            rowptr, csr, bufs[l & 1], disq, gb, Wn, jw,
            bufs[(l + 1) & 1], jkacc16, jkm, NN);
    }
    // layer 5: plain gather -> h16
    k_gather<<<gather_grid, 256, 0, stream>>>(rowptr, csr, bufs[1], disq,
                                              bh + (size_t)4 * 64, h16, NN);

    hipMemsetAsync(pooled, 0, 64 * 64 * sizeof(float), stream);
    k_jkfin_pool<<<GEMM_GRID, 256, 0, stream>>>(h16, jkW + (size_t)5 * 64 * 64, jkacc16,
                                                jkb, batch, pooled, NN);
    k_head<<<NGRAPH, 64, 0, stream>>>(pooled, W1, b1, W2, b2, (float*)d_out);
}

// Round 14
// 529.851 us; speedup vs baseline: 1.4696x; 1.4696x over previous
//
#include <hip/hip_runtime.h>
#include <hip/hip_fp16.h>

#define NN 100000
#define NE 1000000
#define F_INF 128
#define HID 64
#define NLAY 6
#define NCLS 10
#define NGRAPH 64
#define PART_SZ 12500   // NN/8 — contiguous node range per XCD partition
#define SCAT_BLKS (((NE + 2047) / 2048) * 8)   // 489*8 = 3912
#define GEMM_GRID ((NN + 63) / 64)             // 1563

__device__ __forceinline__ float4 h4f(ushort4 u) {
    __half2 lo = *reinterpret_cast<__half2*>(&u);
    __half2 hi = *reinterpret_cast<__half2*>(reinterpret_cast<unsigned short*>(&u) + 2);
    float2 a = __half22float2(lo);
    float2 b = __half22float2(hi);
    return make_float4(a.x, a.y, b.x, b.y);
}

__device__ __forceinline__ ushort4 f4h(float4 v) {
    __half2 lo = __floats2half2_rn(v.x, v.y);
    __half2 hi = __floats2half2_rn(v.z, v.w);
    ushort4 u;
    *reinterpret_cast<__half2*>(&u) = lo;
    *reinterpret_cast<__half2*>(reinterpret_cast<unsigned short*>(&u) + 2) = hi;
    return u;
}

// accumulate 8 fp16 (one 16B chunk) into two float4
__device__ __forceinline__ void acc8(uint4 u, float4& a, float4& b) {
    float2 f0 = __half22float2(*reinterpret_cast<__half2*>(&u.x));
    float2 f1 = __half22float2(*reinterpret_cast<__half2*>(&u.y));
    float2 f2 = __half22float2(*reinterpret_cast<__half2*>(&u.z));
    float2 f3 = __half22float2(*reinterpret_cast<__half2*>(&u.w));
    a.x += f0.x; a.y += f0.y; a.z += f1.x; a.w += f1.y;
    b.x += f2.x; b.y += f2.y; b.z += f3.x; b.w += f3.y;
}

__device__ __forceinline__ uint4 pack8(float4 a, float4 b) {
    uint4 u;
    __half2 h;
    h = __floats2half2_rn(a.x, a.y); u.x = *reinterpret_cast<unsigned*>(&h);
    h = __floats2half2_rn(a.z, a.w); u.y = *reinterpret_cast<unsigned*>(&h);
    h = __floats2half2_rn(b.x, b.y); u.z = *reinterpret_cast<unsigned*>(&h);
    h = __floats2half2_rn(b.z, b.w); u.w = *reinterpret_cast<unsigned*>(&h);
    return u;
}

// ================= CSR build =================
__global__ void k_hist(const int* __restrict__ dst, int* __restrict__ counts, int e) {
    int i0 = blockIdx.x * 1024 + threadIdx.x;
    #pragma unroll
    for (int k = 0; k < 4; k++) {
        int i = i0 + k * 256;
        if (i < e) atomicAdd(&counts[dst[i]], 1);
    }
}

__global__ void k_blocksum(const int* __restrict__ counts, int* __restrict__ bsum, int n) {
    int i = blockIdx.x * 256 + threadIdx.x;
    int v = (i < n) ? counts[i] : 0;
    #pragma unroll
    for (int off = 32; off >= 1; off >>= 1) v += __shfl_down(v, off);
    __shared__ int ws[4];
    if ((threadIdx.x & 63) == 0) ws[threadIdx.x >> 6] = v;
    __syncthreads();
    if (threadIdx.x == 0) bsum[blockIdx.x] = ws[0] + ws[1] + ws[2] + ws[3];
}

__global__ void k_scanbsum(int* __restrict__ bsum, int nb) {   // 1 block, 512 thr
    __shared__ int sh[512];
    int t = threadIdx.x;
    int v = (t < nb) ? bsum[t] : 0;
    sh[t] = v; __syncthreads();
    for (int off = 1; off < 512; off <<= 1) {
        int x = (t >= off) ? sh[t - off] : 0;
        __syncthreads();
        sh[t] += x; __syncthreads();
    }
    if (t < nb) bsum[t] = sh[t] - v;   // exclusive
}

__global__ void k_scanwrite(const int* __restrict__ counts, const int* __restrict__ bsumx,
                            int* __restrict__ rowptr, int* __restrict__ wptr,
                            float* __restrict__ disq, int n, int e) {
    __shared__ int sh[256];
    int t = threadIdx.x;
    int i = blockIdx.x * 256 + t;
    int v = (i < n) ? counts[i] : 0;
    sh[t] = v; __syncthreads();
    for (int off = 1; off < 256; off <<= 1) {
        int x = (t >= off) ? sh[t - off] : 0;
        __syncthreads();
        sh[t] += x; __syncthreads();
    }
    int excl = sh[t] - v + bsumx[blockIdx.x];
    if (i < n) {
        rowptr[i] = excl;
        wptr[i]   = excl;
        disq[i]   = rsqrtf((float)(v + 1));   // +1 self-loop
    }
    if (i == 0) rowptr[n] = e;
}

// ============ fused: XCD-partitioned scatter + layer-0 GEMM (17KB LDS, K-chunk=32) ============
__global__ __launch_bounds__(256) void k_scatter_gemm0(
    const int* __restrict__ src, const int* __restrict__ dst,
    int* __restrict__ wptr, int* __restrict__ csr, int e,
    const float* __restrict__ x, const float* __restrict__ W0,
    const float* __restrict__ disq, unsigned short* __restrict__ C16, int n)
{
    __shared__ float Ws[32 * 64];
    __shared__ float As[64 * 36];

    if (blockIdx.x < SCAT_BLKS) {
        int part = blockIdx.x & 7;
        int i0 = (blockIdx.x >> 3) * 2048 + threadIdx.x;
        #pragma unroll
        for (int k = 0; k < 8; k++) {
            int i = i0 + k * 256;
            if (i < e) {
                int d = dst[i];
                if (d / PART_SZ == part) {
                    int pos = atomicAdd(&wptr[d], 1);
                    csr[pos] = src[i];
                }
            }
        }
        return;
    }

    const int tid  = threadIdx.x;
    const int col4 = (tid & 15) * 4;
    const int rowq = tid >> 4;
    const int base = (blockIdx.x - SCAT_BLKS) * 64;
    const int ar   = tid >> 3;
    const int ac4  = (tid & 7) * 4;

    float4 wreg[2], areg[2];
    #pragma unroll
    for (int i = 0; i < 2; i++)
        wreg[i] = *(const float4*)(W0 + (size_t)(i * 256 + tid) * 4);
    #pragma unroll
    for (int rr = 0; rr < 2; rr++) {
        int row = base + ar + rr * 32;
        areg[rr] = make_float4(0.f, 0.f, 0.f, 0.f);
        if (row < n) areg[rr] = *(const float4*)(x + (size_t)row * F_INF + ac4);
    }
    #pragma unroll
    for (int i = 0; i < 2; i++)
        *(float4*)(Ws + (size_t)(i * 256 + tid) * 4) = wreg[i];
    #pragma unroll
    for (int rr = 0; rr < 2; rr++)
        *(float4*)(As + (size_t)(ar + rr * 32) * 36 + ac4) = areg[rr];
    __syncthreads();

    float4 acc[4];
    #pragma unroll
    for (int r = 0; r < 4; r++) acc[r] = make_float4(0.f, 0.f, 0.f, 0.f);

    for (int k0 = 0; k0 < F_INF; k0 += 32) {
        const bool more = (k0 + 32) < F_INF;
        if (more) {
            #pragma unroll
            for (int i = 0; i < 2; i++)
                wreg[i] = *(const float4*)(W0 + (size_t)(k0 + 32) * 64 + (i * 256 + tid) * 4);
            #pragma unroll
            for (int rr = 0; rr < 2; rr++) {
                int row = base + ar + rr * 32;
                areg[rr] = make_float4(0.f, 0.f, 0.f, 0.f);
                if (row < n) areg[rr] = *(const float4*)(x + (size_t)row * F_INF + k0 + 32 + ac4);
            }
        }
        #pragma unroll 8
        for (int k = 0; k < 32; k++) {
            float4 w = *(const float4*)(Ws + k * 64 + col4);
            float a0 = As[(rowq * 4 + 0) * 36 + k];
            float a1 = As[(rowq * 4 + 1) * 36 + k];
            float a2 = As[(rowq * 4 + 2) * 36 + k];
            float a3 = As[(rowq * 4 + 3) * 36 + k];
            acc[0].x = fmaf(a0, w.x, acc[0].x); acc[0].y = fmaf(a0, w.y, acc[0].y);
            acc[0].z = fmaf(a0, w.z, acc[0].z); acc[0].w = fmaf(a0, w.w, acc[0].w);
            acc[1].x = fmaf(a1, w.x, acc[1].x); acc[1].y = fmaf(a1, w.y, acc[1].y);
            acc[1].z = fmaf(a1, w.z, acc[1].z); acc[1].w = fmaf(a1, w.w, acc[1].w);
            acc[2].x = fmaf(a2, w.x, acc[2].x); acc[2].y = fmaf(a2, w.y, acc[2].y);
            acc[2].z = fmaf(a2, w.z, acc[2].z); acc[2].w = fmaf(a2, w.w, acc[2].w);
            acc[3].x = fmaf(a3, w.x, acc[3].x); acc[3].y = fmaf(a3, w.y, acc[3].y);
            acc[3].z = fmaf(a3, w.z, acc[3].z); acc[3].w = fmaf(a3, w.w, acc[3].w);
        }
        __syncthreads();
        if (more) {
            #pragma unroll
            for (int i = 0; i < 2; i++)
                *(float4*)(Ws + (size_t)(i * 256 + tid) * 4) = wreg[i];
            #pragma unroll
            for (int rr = 0; rr < 2; rr++)
                *(float4*)(As + (size_t)(ar + rr * 32) * 36 + ac4) = areg[rr];
            __syncthreads();
        }
    }

    #pragma unroll
    for (int r = 0; r < 4; r++) {
        int row = base + rowq * 4 + r;
        if (row < n) {
            float s = disq[row];
            float4 o;
            o.x = acc[r].x * s; o.y = acc[r].y * s;
            o.z = acc[r].z * s; o.w = acc[r].w * s;
            ((ushort4*)C16)[(size_t)row * 16 + (tid & 15)] = f4h(o);
        }
    }
}

// ============ dual GEMM layers 1-5 (K=64, fp16 A): C16 and jkacc (fp16) ============
__global__ __launch_bounds__(256) void k_gemm_dual(
    const unsigned short* __restrict__ A16,
    const float* __restrict__ W,
    const float* __restrict__ jkw,
    const float* __restrict__ disq,
    unsigned short* __restrict__ C16,
    unsigned short* __restrict__ jkacc16,
    int jk_mode, int n)
{
    __shared__ float Ws[64 * 64];
    __shared__ float Ws2[64 * 64];
    __shared__ float As[64 * 68];
    const int tid  = threadIdx.x;
    const int col4 = (tid & 15) * 4;
    const int rowq = tid >> 4;
    const int base = blockIdx.x * 64;

    #pragma unroll
    for (int i = 0; i < 4; i++) {
        float4 v = *(const float4*)(W + (size_t)(i * 256 + tid) * 4);
        *(float4*)(Ws + (size_t)(i * 256 + tid) * 4) = v;
        float4 v2 = *(const float4*)(jkw + (size_t)(i * 256 + tid) * 4);
        *(float4*)(Ws2 + (size_t)(i * 256 + tid) * 4) = v2;
    }
    {
        const ushort4* Ah = (const ushort4*)A16;
        #pragma unroll
        for (int rr = 0; rr < 4; rr++) {
            int row = base + rowq + rr * 16;
            float4 v = make_float4(0.f, 0.f, 0.f, 0.f);
            if (row < n) v = h4f(Ah[(size_t)row * 16 + (tid & 15)]);
            *(float4*)(As + (size_t)(rowq + rr * 16) * 68 + col4) = v;
        }
    }
    __syncthreads();

    float4 acc[4], acc2[4];
    #pragma unroll
    for (int r = 0; r < 4; r++) {
        acc[r]  = make_float4(0.f, 0.f, 0.f, 0.f);
        acc2[r] = make_float4(0.f, 0.f, 0.f, 0.f);
    }

    #pragma unroll 4
    for (int k = 0; k < 64; k++) {
        float4 w  = *(const float4*)(Ws  + k * 64 + col4);
        float4 w2 = *(const float4*)(Ws2 + k * 64 + col4);
        float a0 = As[(rowq * 4 + 0) * 68 + k];
        float a1 = As[(rowq * 4 + 1) * 68 + k];
        float a2 = As[(rowq * 4 + 2) * 68 + k];
        float a3 = As[(rowq * 4 + 3) * 68 + k];
        acc[0].x = fmaf(a0, w.x, acc[0].x); acc[0].y = fmaf(a0, w.y, acc[0].y);
        acc[0].z = fmaf(a0, w.z, acc[0].z); acc[0].w = fmaf(a0, w.w, acc[0].w);
        acc[1].x = fmaf(a1, w.x, acc[1].x); acc[1].y = fmaf(a1, w.y, acc[1].y);
        acc[1].z = fmaf(a1, w.z, acc[1].z); acc[1].w = fmaf(a1, w.w, acc[1].w);
        acc[2].x = fmaf(a2, w.x, acc[2].x); acc[2].y = fmaf(a2, w.y, acc[2].y);
        acc[2].z = fmaf(a2, w.z, acc[2].z); acc[2].w = fmaf(a2, w.w, acc[2].w);
        acc[3].x = fmaf(a3, w.x, acc[3].x); acc[3].y = fmaf(a3, w.y, acc[3].y);
        acc[3].z = fmaf(a3, w.z, acc[3].z); acc[3].w = fmaf(a3, w.w, acc[3].w);
        acc2[0].x = fmaf(a0, w2.x, acc2[0].x); acc2[0].y = fmaf(a0, w2.y, acc2[0].y);
        acc2[0].z = fmaf(a0, w2.z, acc2[0].z); acc2[0].w = fmaf(a0, w2.w, acc2[0].w);
        acc2[1].x = fmaf(a1, w2.x, acc2[1].x); acc2[1].y = fmaf(a1, w2.y, acc2[1].y);
        acc2[1].z = fmaf(a1, w2.z, acc2[1].z); acc2[1].w = fmaf(a1, w2.w, acc2[1].w);
        acc2[2].x = fmaf(a2, w2.x, acc2[2].x); acc2[2].y = fmaf(a2, w2.y, acc2[2].y);
        acc2[2].z = fmaf(a2, w2.z, acc2[2].z); acc2[2].w = fmaf(a2, w2.w, acc2[2].w);
        acc2[3].x = fmaf(a3, w2.x, acc2[3].x); acc2[3].y = fmaf(a3, w2.y, acc2[3].y);
        acc2[3].z = fmaf(a3, w2.z, acc2[3].z); acc2[3].w = fmaf(a3, w2.w, acc2[3].w);
    }

    #pragma unroll
    for (int r = 0; r < 4; r++) {
        int row = base + rowq * 4 + r;
        if (row < n) {
            float s = disq[row];
            float4 o;
            o.x = acc[r].x * s; o.y = acc[r].y * s;
            o.z = acc[r].z * s; o.w = acc[r].w * s;
            ((ushort4*)C16)[(size_t)row * 16 + (tid & 15)] = f4h(o);
            if (jk_mode == 1) {
                ((ushort4*)jkacc16)[(size_t)row * 16 + (tid & 15)] = f4h(acc2[r]);
            } else {
                float4 p = h4f(((const ushort4*)jkacc16)[(size_t)row * 16 + (tid & 15)]);
                p.x += acc2[r].x; p.y += acc2[r].y;
                p.z += acc2[r].z; p.w += acc2[r].w;
                ((ushort4*)jkacc16)[(size_t)row * 16 + (tid & 15)] = f4h(p);
            }
        }
    }
}

// ============ gather: wave per node, 16B loads, 8 edge slots, 32 edges in flight ============
__global__ __launch_bounds__(256) void k_gather(
    const int* __restrict__ rowptr, const int* __restrict__ csr,
    const unsigned short* __restrict__ hW16, const float* __restrict__ disq,
    const float* __restrict__ bias, unsigned short* __restrict__ hout16, int n)
{
    const uint4* hW = (const uint4*)hW16;    // row = 8 x 16B chunks
    int wid  = (blockIdx.x * 256 + threadIdx.x) >> 6;
    if (wid >= n) return;
    int lane = threadIdx.x & 63;
    int fb = lane & 7;        // 16B chunk index within 128B row
    int es = lane >> 3;       // edge slot 0..7
    int j  = rowptr[wid];
    int r1 = rowptr[wid + 1];
    float4 va = make_float4(0.f, 0.f, 0.f, 0.f), vb = va, vc = va, vd = va;
    if (es == 0) {                                  // self-loop
        uint4 u = hW[(size_t)wid * 8 + fb];
        acc8(u, va, vb);
    }
    while (j < r1) {
        int cnt = min(r1 - j, 64);
        int idx = (lane < cnt) ? csr[j + lane] : 0;
        for (int jj = 0; jj < cnt; jj += 32) {
            int i0 = jj + es, i1 = jj + 8 + es, i2 = jj + 16 + es, i3 = jj + 24 + es;
            int s0 = __shfl(idx, i0 & 63);
            int s1 = __shfl(idx, i1 & 63);
            int s2 = __shfl(idx, i2 & 63);
            int s3 = __shfl(idx, i3 & 63);
            uint4 t0 = hW[(size_t)s0 * 8 + fb];
            uint4 t1 = hW[(size_t)s1 * 8 + fb];
            uint4 t2 = hW[(size_t)s2 * 8 + fb];
            uint4 t3 = hW[(size_t)s3 * 8 + fb];
            if (i0 < cnt) acc8(t0, va, vb);
            if (i1 < cnt) acc8(t1, vc, vd);
            if (i2 < cnt) acc8(t2, va, vb);
            if (i3 < cnt) acc8(t3, vc, vd);
        }
        j += cnt;
    }
    va.x += vc.x; va.y += vc.y; va.z += vc.z; va.w += vc.w;
    vb.x += vd.x; vb.y += vd.y; vb.z += vd.z; vb.w += vd.w;
    #pragma unroll
    for (int off = 8; off <= 32; off <<= 1) {
        va.x += __shfl_xor(va.x, off); va.y += __shfl_xor(va.y, off);
        va.z += __shfl_xor(va.z, off); va.w += __shfl_xor(va.w, off);
        vb.x += __shfl_xor(vb.x, off); vb.y += __shfl_xor(vb.y, off);
        vb.z += __shfl_xor(vb.z, off); vb.w += __shfl_xor(vb.w, off);
    }
    if (es == 0) {
        float s = disq[wid];
        float4 b0 = ((const float4*)bias)[fb * 2];
        float4 b1 = ((const float4*)bias)[fb * 2 + 1];
        float4 oa, ob;
        oa.x = fmaxf(fmaf(s, va.x, b0.x), 0.f);
        oa.y = fmaxf(fmaf(s, va.y, b0.y), 0.f);
        oa.z = fmaxf(fmaf(s, va.z, b0.z), 0.f);
        oa.w = fmaxf(fmaf(s, va.w, b0.w), 0.f);
        ob.x = fmaxf(fmaf(s, vb.x, b1.x), 0.f);
        ob.y = fmaxf(fmaf(s, vb.y, b1.y), 0.f);
        ob.z = fmaxf(fmaf(s, vb.z, b1.z), 0.f);
        ob.w = fmaxf(fmaf(s, vb.w, b1.w), 0.f);
        ((uint4*)hout16)[(size_t)wid * 8 + fb] = pack8(oa, ob);
    }
}

// ============ final: t = relu(h@jkW5 + jkacc + jkb); pool by batch ============
__global__ __launch_bounds__(256) void k_jkfin_pool(
    const unsigned short* __restrict__ A16,
    const float* __restrict__ W,
    const unsigned short* __restrict__ jkacc16,
    const float* __restrict__ bias,
    const int* __restrict__ batch,
    float* __restrict__ pooled,
    int n)
{
    __shared__ float Ws[64 * 64];
    __shared__ float As[64 * 68];
    const int tid  = threadIdx.x;
    const int col4 = (tid & 15) * 4;
    const int rowq = tid >> 4;
    const int base = blockIdx.x * 64;

    #pragma unroll
    for (int i = 0; i < 4; i++) {
        float4 v = *(const float4*)(W + (size_t)(i * 256 + tid) * 4);
        *(float4*)(Ws + (size_t)(i * 256 + tid) * 4) = v;
    }
    {
        const ushort4* Ah = (const ushort4*)A16;
        #pragma unroll
        for (int rr = 0; rr < 4; rr++) {
            int row = base + rowq + rr * 16;
            float4 v = make_float4(0.f, 0.f, 0.f, 0.f);
            if (row < n) v = h4f(Ah[(size_t)row * 16 + (tid & 15)]);
            *(float4*)(As + (size_t)(rowq + rr * 16) * 68 + col4) = v;
        }
    }
    __syncthreads();

    float4 acc[4];
    #pragma unroll
    for (int r = 0; r < 4; r++) acc[r] = make_float4(0.f, 0.f, 0.f, 0.f);
    #pragma unroll 8
    for (int k = 0; k < 64; k++) {
        float4 w = *(const float4*)(Ws + k * 64 + col4);
        float a0 = As[(rowq * 4 + 0) * 68 + k];
        float a1 = As[(rowq * 4 + 1) * 68 + k];
        float a2 = As[(rowq * 4 + 2) * 68 + k];
        float a3 = As[(rowq * 4 + 3) * 68 + k];
        acc[0].x = fmaf(a0, w.x, acc[0].x); acc[0].y = fmaf(a0, w.y, acc[0].y);
        acc[0].z = fmaf(a0, w.z, acc[0].z); acc[0].w = fmaf(a0, w.w, acc[0].w);
        acc[1].x = fmaf(a1, w.x, acc[1].x); acc[1].y = fmaf(a1, w.y, acc[1].y);
        acc[1].z = fmaf(a1, w.z, acc[1].z); acc[1].w = fmaf(a1, w.w, acc[1].w);
        acc[2].x = fmaf(a2, w.x, acc[2].x); acc[2].y = fmaf(a2, w.y, acc[2].y);
        acc[2].z = fmaf(a2, w.z, acc[2].z); acc[2].w = fmaf(a2, w.w, acc[2].w);
        acc[3].x = fmaf(a3, w.x, acc[3].x); acc[3].y = fmaf(a3, w.y, acc[3].y);
        acc[3].z = fmaf(a3, w.z, acc[3].z); acc[3].w = fmaf(a3, w.w, acc[3].w);
    }
    __syncthreads();

    float* slab = Ws;
    #pragma unroll
    for (int i = tid; i < 4096; i += 256) slab[i] = 0.f;
    __syncthreads();

    float4 bb = *(const float4*)(bias + col4);
    int curg = -1;
    float4 s4 = make_float4(0.f, 0.f, 0.f, 0.f);
    #pragma unroll
    for (int r = 0; r < 4; r++) {
        int row = base + rowq * 4 + r;
        if (row < n) {
            float4 p = h4f(((const ushort4*)jkacc16)[(size_t)row * 16 + (tid & 15)]);
            float4 vv;
            vv.x = fmaxf(acc[r].x + p.x + bb.x, 0.f);
            vv.y = fmaxf(acc[r].y + p.y + bb.y, 0.f);
            vv.z = fmaxf(acc[r].z + p.z + bb.z, 0.f);
            vv.w = fmaxf(acc[r].w + p.w + bb.w, 0.f);
            int g = batch[row];
            if (g != curg) {
                if (curg >= 0) {
                    atomicAdd(&slab[curg * 64 + col4 + 0], s4.x);
                    atomicAdd(&slab[curg * 64 + col4 + 1], s4.y);
                    atomicAdd(&slab[curg * 64 + col4 + 2], s4.z);
                    atomicAdd(&slab[curg * 64 + col4 + 3], s4.w);
                }
                curg = g; s4 = vv;
            } else {
                s4.x += vv.x; s4.y += vv.y; s4.z += vv.z; s4.w += vv.w;
            }
        }
    }
    if (curg >= 0) {
        atomicAdd(&slab[curg * 64 + col4 + 0], s4.x);
        atomicAdd(&slab[curg * 64 + col4 + 1], s4.y);
        atomicAdd(&slab[curg * 64 + col4 + 2], s4.z);
        atomicAdd(&slab[curg * 64 + col4 + 3], s4.w);
    }
    __syncthreads();

    int g0 = batch[base];
    int g1 = batch[(base + 63 < n) ? (base + 63) : (n - 1)];
    int cnt = (g1 - g0 + 1) * 64;
    for (int i = tid; i < cnt; i += 256) {
        int g = g0 + (i >> 6);
        int c = i & 63;
        float v = slab[g * 64 + c];
        if (v != 0.f) atomicAdd(&pooled[g * 64 + c], v);
    }
}

// ============ head ============
__global__ __launch_bounds__(64) void k_head(
    const float* __restrict__ pooled,
    const float* __restrict__ W1, const float* __restrict__ b1,
    const float* __restrict__ W2, const float* __restrict__ b2,
    float* __restrict__ out)
{
    __shared__ float p[64];
    __shared__ float h1[64];
    __shared__ float lg[16];
    const int g = blockIdx.x;
    const int t = threadIdx.x;

    p[t] = pooled[g * 64 + t];
    __syncthreads();

    float acc = b1[t];
    #pragma unroll 8
    for (int k = 0; k < 64; k++) acc = fmaf(p[k], W1[k * 64 + t], acc);
    h1[t] = fmaxf(acc, 0.f);
    __syncthreads();

    if (t < NCLS) {
        float a = b2[t];
        #pragma unroll 8
        for (int j = 0; j < 64; j++) a = fmaf(h1[j], W2[j * NCLS + t], a);
        lg[t] = a;
    }
    __syncthreads();

    if (t == 0) {
        float mx = lg[0];
        #pragma unroll
        for (int c = 1; c < NCLS; c++) mx = fmaxf(mx, lg[c]);
        float ssum = 0.f;
        float e[NCLS];
        #pragma unroll
        for (int c = 0; c < NCLS; c++) { e[c] = __expf(lg[c] - mx); ssum += e[c]; }
        float inv = 1.0f / ssum;
        #pragma unroll
        for (int c = 0; c < NCLS; c++) out[g * NCLS + c] = e[c] * inv;
    }
}

extern "C" void kernel_launch(void* const* d_in, const int* in_sizes, int n_in,
                              void* d_out, int out_size, void* d_ws, size_t ws_size,
                              hipStream_t stream) {
    (void)in_sizes; (void)n_in; (void)out_size; (void)ws_size;
    const float* x     = (const float*)d_in[0];
    const int*   ei    = (const int*)d_in[1];
    const int*   batch = (const int*)d_in[2];
    const float* W0    = (const float*)d_in[3];
    const float* b0    = (const float*)d_in[4];
    const float* Wh    = (const float*)d_in[5];
    const float* bh    = (const float*)d_in[6];
    const float* jkW   = (const float*)d_in[7];
    const float* jkb   = (const float*)d_in[8];
    const float* W1    = (const float*)d_in[9];
    const float* b1    = (const float*)d_in[10];
    const float* W2    = (const float*)d_in[11];
    const float* b2    = (const float*)d_in[12];

    const int* src = ei;
    const int* dst = ei + NE;

    float*          fws     = (float*)d_ws;
    float*          disq    = fws;
    unsigned short* hWb     = (unsigned short*)(disq + 100352);
    unsigned short* h16     = hWb + (size_t)NN * 64;
    unsigned short* jkacc16 = h16 + (size_t)NN * 64;
    float*          pooled  = (float*)(jkacc16 + (size_t)NN * 64);
    int*            counts  = (int*)(pooled + 4096);
    int*            rowptr  = counts + 100352;
    int*            wptr    = rowptr + 100352;
    int*            bsum    = wptr + 100352;
    int*            csr     = bsum + 512;

    const int NB_N = (NN + 255) / 256;

    hipMemsetAsync(counts, 0, (size_t)NN * sizeof(int), stream);
    k_hist<<<(NE + 1023) / 1024, 256, 0, stream>>>(dst, counts, NE);
    k_blocksum<<<NB_N, 256, 0, stream>>>(counts, bsum, NN);
    k_scanbsum<<<1, 512, 0, stream>>>(bsum, NB_N);
    k_scanwrite<<<NB_N, 256, 0, stream>>>(counts, bsum, rowptr, wptr, disq, NN, NE);

    // fused scatter + layer-0 GEMM
    k_scatter_gemm0<<<SCAT_BLKS + GEMM_GRID, 256, 0, stream>>>(
        src, dst, wptr, csr, NE, x, W0, disq, hWb, NN);

    const int gather_grid = (NN + 3) / 4;
    k_gather<<<gather_grid, 256, 0, stream>>>(rowptr, csr, hWb, disq, b0, h16, NN);
    for (int l = 1; l < NLAY; l++) {
        const float* W   = Wh + (size_t)(l - 1) * 64 * 64;
        const float* jw  = jkW + (size_t)(l - 1) * 64 * 64;
        int          jkm = (l == 1) ? 1 : 2;
        k_gemm_dual<<<GEMM_GRID, 256, 0, stream>>>(h16, W, jw, disq, hWb, jkacc16, jkm, NN);
        k_gather<<<gather_grid, 256, 0, stream>>>(rowptr, csr, hWb, disq,
                                                  bh + (size_t)(l - 1) * 64, h16, NN);
    }

    hipMemsetAsync(pooled, 0, 64 * 64 * sizeof(float), stream);
    k_jkfin_pool<<<GEMM_GRID, 256, 0, stream>>>(h16, jkW + (size_t)5 * 64 * 64, jkacc16,
                                                jkb, batch, pooled, NN);
    k_head<<<NGRAPH, 64, 0, stream>>>(pooled, W1, b1, W2, b2, (float*)d_out);
}

// Round 15
// 521.285 us; speedup vs baseline: 1.4938x; 1.0164x over previous
//
#include <hip/hip_runtime.h>
#include <hip/hip_fp16.h>

#define NN 100000
#define NE 1000000
#define F_INF 128
#define HID 64
#define NLAY 6
#define NCLS 10
#define NGRAPH 64
#define PART_SZ 12500   // NN/8 — contiguous node range per XCD partition
#define SCAT_BLKS (((NE + 2047) / 2048) * 8)   // 489*8 = 3912
#define GEMM_GRID ((NN + 63) / 64)             // 1563

__device__ __forceinline__ float4 h4f(ushort4 u) {
    __half2 lo = *reinterpret_cast<__half2*>(&u);
    __half2 hi = *reinterpret_cast<__half2*>(reinterpret_cast<unsigned short*>(&u) + 2);
    float2 a = __half22float2(lo);
    float2 b = __half22float2(hi);
    return make_float4(a.x, a.y, b.x, b.y);
}

__device__ __forceinline__ ushort4 f4h(float4 v) {
    __half2 lo = __floats2half2_rn(v.x, v.y);
    __half2 hi = __floats2half2_rn(v.z, v.w);
    ushort4 u;
    *reinterpret_cast<__half2*>(&u) = lo;
    *reinterpret_cast<__half2*>(reinterpret_cast<unsigned short*>(&u) + 2) = hi;
    return u;
}

// ================= CSR build =================
__global__ void k_hist(const int* __restrict__ dst, int* __restrict__ counts, int e) {
    int i0 = blockIdx.x * 1024 + threadIdx.x;
    #pragma unroll
    for (int k = 0; k < 4; k++) {
        int i = i0 + k * 256;
        if (i < e) atomicAdd(&counts[dst[i]], 1);
    }
}

__global__ void k_blocksum(const int* __restrict__ counts, int* __restrict__ bsum, int n) {
    int i = blockIdx.x * 256 + threadIdx.x;
    int v = (i < n) ? counts[i] : 0;
    #pragma unroll
    for (int off = 32; off >= 1; off >>= 1) v += __shfl_down(v, off);
    __shared__ int ws[4];
    if ((threadIdx.x & 63) == 0) ws[threadIdx.x >> 6] = v;
    __syncthreads();
    if (threadIdx.x == 0) bsum[blockIdx.x] = ws[0] + ws[1] + ws[2] + ws[3];
}

__global__ void k_scanbsum(int* __restrict__ bsum, int nb) {   // 1 block, 512 thr
    __shared__ int sh[512];
    int t = threadIdx.x;
    int v = (t < nb) ? bsum[t] : 0;
    sh[t] = v; __syncthreads();
    for (int off = 1; off < 512; off <<= 1) {
        int x = (t >= off) ? sh[t - off] : 0;
        __syncthreads();
        sh[t] += x; __syncthreads();
    }
    if (t < nb) bsum[t] = sh[t] - v;   // exclusive
}

__global__ void k_scanwrite(const int* __restrict__ counts, const int* __restrict__ bsumx,
                            int* __restrict__ rowptr, int* __restrict__ wptr,
                            float* __restrict__ disq, int n, int e) {
    __shared__ int sh[256];
    int t = threadIdx.x;
    int i = blockIdx.x * 256 + t;
    int v = (i < n) ? counts[i] : 0;
    sh[t] = v; __syncthreads();
    for (int off = 1; off < 256; off <<= 1) {
        int x = (t >= off) ? sh[t - off] : 0;
        __syncthreads();
        sh[t] += x; __syncthreads();
    }
    int excl = sh[t] - v + bsumx[blockIdx.x];
    if (i < n) {
        rowptr[i] = excl;
        wptr[i]   = excl;
        disq[i]   = rsqrtf((float)(v + 1));   // +1 self-loop
    }
    if (i == 0) rowptr[n] = e;
}

// ============ fused: layer-0 GEMM (blocks FIRST) + XCD-partitioned scatter ============
// GEMM blocks dispatch first so scatter (atomic-bound, zero-VALU) co-resides with
// GEMM (VALU-bound) from t=0 — complementary pipes overlap instead of serializing.
__global__ __launch_bounds__(256) void k_scatter_gemm0(
    const int* __restrict__ src, const int* __restrict__ dst,
    int* __restrict__ wptr, int* __restrict__ csr, int e,
    const float* __restrict__ x, const float* __restrict__ W0,
    const float* __restrict__ disq, unsigned short* __restrict__ C16, int n)
{
    __shared__ float Ws[32 * 64];    // 8KB
    __shared__ float As[64 * 36];    // 9.2KB

    if (blockIdx.x >= GEMM_GRID) {
        // ---- scatter ----
        int sbid = blockIdx.x - GEMM_GRID;
        int part = sbid & 7;
        int i0 = (sbid >> 3) * 2048 + threadIdx.x;
        #pragma unroll
        for (int k = 0; k < 8; k++) {
            int i = i0 + k * 256;
            if (i < e) {
                int d = dst[i];
                if (d / PART_SZ == part) {
                    int pos = atomicAdd(&wptr[d], 1);
                    csr[pos] = src[i];
                }
            }
        }
        return;
    }

    // ---- layer-0 GEMM, K-chunk=32 ----
    const int tid  = threadIdx.x;
    const int col4 = (tid & 15) * 4;
    const int rowq = tid >> 4;
    const int base = blockIdx.x * 64;
    const int ar   = tid >> 3;
    const int ac4  = (tid & 7) * 4;

    float4 wreg[2], areg[2];
    #pragma unroll
    for (int i = 0; i < 2; i++)
        wreg[i] = *(const float4*)(W0 + (size_t)(i * 256 + tid) * 4);
    #pragma unroll
    for (int rr = 0; rr < 2; rr++) {
        int row = base + ar + rr * 32;
        areg[rr] = make_float4(0.f, 0.f, 0.f, 0.f);
        if (row < n) areg[rr] = *(const float4*)(x + (size_t)row * F_INF + ac4);
    }
    #pragma unroll
    for (int i = 0; i < 2; i++)
        *(float4*)(Ws + (size_t)(i * 256 + tid) * 4) = wreg[i];
    #pragma unroll
    for (int rr = 0; rr < 2; rr++)
        *(float4*)(As + (size_t)(ar + rr * 32) * 36 + ac4) = areg[rr];
    __syncthreads();

    float4 acc[4];
    #pragma unroll
    for (int r = 0; r < 4; r++) acc[r] = make_float4(0.f, 0.f, 0.f, 0.f);

    for (int k0 = 0; k0 < F_INF; k0 += 32) {
        const bool more = (k0 + 32) < F_INF;
        if (more) {
            #pragma unroll
            for (int i = 0; i < 2; i++)
                wreg[i] = *(const float4*)(W0 + (size_t)(k0 + 32) * 64 + (i * 256 + tid) * 4);
            #pragma unroll
            for (int rr = 0; rr < 2; rr++) {
                int row = base + ar + rr * 32;
                areg[rr] = make_float4(0.f, 0.f, 0.f, 0.f);
                if (row < n) areg[rr] = *(const float4*)(x + (size_t)row * F_INF + k0 + 32 + ac4);
            }
        }
        #pragma unroll 8
        for (int k = 0; k < 32; k++) {
            float4 w = *(const float4*)(Ws + k * 64 + col4);
            float a0 = As[(rowq * 4 + 0) * 36 + k];
            float a1 = As[(rowq * 4 + 1) * 36 + k];
            float a2 = As[(rowq * 4 + 2) * 36 + k];
            float a3 = As[(rowq * 4 + 3) * 36 + k];
            acc[0].x = fmaf(a0, w.x, acc[0].x); acc[0].y = fmaf(a0, w.y, acc[0].y);
            acc[0].z = fmaf(a0, w.z, acc[0].z); acc[0].w = fmaf(a0, w.w, acc[0].w);
            acc[1].x = fmaf(a1, w.x, acc[1].x); acc[1].y = fmaf(a1, w.y, acc[1].y);
            acc[1].z = fmaf(a1, w.z, acc[1].z); acc[1].w = fmaf(a1, w.w, acc[1].w);
            acc[2].x = fmaf(a2, w.x, acc[2].x); acc[2].y = fmaf(a2, w.y, acc[2].y);
            acc[2].z = fmaf(a2, w.z, acc[2].z); acc[2].w = fmaf(a2, w.w, acc[2].w);
            acc[3].x = fmaf(a3, w.x, acc[3].x); acc[3].y = fmaf(a3, w.y, acc[3].y);
            acc[3].z = fmaf(a3, w.z, acc[3].z); acc[3].w = fmaf(a3, w.w, acc[3].w);
        }
        __syncthreads();
        if (more) {
            #pragma unroll
            for (int i = 0; i < 2; i++)
                *(float4*)(Ws + (size_t)(i * 256 + tid) * 4) = wreg[i];
            #pragma unroll
            for (int rr = 0; rr < 2; rr++)
                *(float4*)(As + (size_t)(ar + rr * 32) * 36 + ac4) = areg[rr];
            __syncthreads();
        }
    }

    #pragma unroll
    for (int r = 0; r < 4; r++) {
        int row = base + rowq * 4 + r;
        if (row < n) {
            float s = disq[row];
            float4 o;
            o.x = acc[r].x * s; o.y = acc[r].y * s;
            o.z = acc[r].z * s; o.w = acc[r].w * s;
            ((ushort4*)C16)[(size_t)row * 16 + (tid & 15)] = f4h(o);
        }
    }
}

// ============ dual GEMM layers 1-5 (K=64, fp16 A): C16 and jkacc (fp16) ============
__global__ __launch_bounds__(256) void k_gemm_dual(
    const unsigned short* __restrict__ A16,
    const float* __restrict__ W,
    const float* __restrict__ jkw,
    const float* __restrict__ disq,
    unsigned short* __restrict__ C16,
    unsigned short* __restrict__ jkacc16,
    int jk_mode, int n)
{
    __shared__ float Ws[64 * 64];
    __shared__ float Ws2[64 * 64];
    __shared__ float As[64 * 68];
    const int tid  = threadIdx.x;
    const int col4 = (tid & 15) * 4;
    const int rowq = tid >> 4;
    const int base = blockIdx.x * 64;

    #pragma unroll
    for (int i = 0; i < 4; i++) {
        float4 v = *(const float4*)(W + (size_t)(i * 256 + tid) * 4);
        *(float4*)(Ws + (size_t)(i * 256 + tid) * 4) = v;
        float4 v2 = *(const float4*)(jkw + (size_t)(i * 256 + tid) * 4);
        *(float4*)(Ws2 + (size_t)(i * 256 + tid) * 4) = v2;
    }
    {
        const ushort4* Ah = (const ushort4*)A16;
        #pragma unroll
        for (int rr = 0; rr < 4; rr++) {
            int row = base + rowq + rr * 16;
            float4 v = make_float4(0.f, 0.f, 0.f, 0.f);
            if (row < n) v = h4f(Ah[(size_t)row * 16 + (tid & 15)]);
            *(float4*)(As + (size_t)(rowq + rr * 16) * 68 + col4) = v;
        }
    }
    __syncthreads();

    float4 acc[4], acc2[4];
    #pragma unroll
    for (int r = 0; r < 4; r++) {
        acc[r]  = make_float4(0.f, 0.f, 0.f, 0.f);
        acc2[r] = make_float4(0.f, 0.f, 0.f, 0.f);
    }

    #pragma unroll 4
    for (int k = 0; k < 64; k++) {
        float4 w  = *(const float4*)(Ws  + k * 64 + col4);
        float4 w2 = *(const float4*)(Ws2 + k * 64 + col4);
        float a0 = As[(rowq * 4 + 0) * 68 + k];
        float a1 = As[(rowq * 4 + 1) * 68 + k];
        float a2 = As[(rowq * 4 + 2) * 68 + k];
        float a3 = As[(rowq * 4 + 3) * 68 + k];
        acc[0].x = fmaf(a0, w.x, acc[0].x); acc[0].y = fmaf(a0, w.y, acc[0].y);
        acc[0].z = fmaf(a0, w.z, acc[0].z); acc[0].w = fmaf(a0, w.w, acc[0].w);
        acc[1].x = fmaf(a1, w.x, acc[1].x); acc[1].y = fmaf(a1, w.y, acc[1].y);
        acc[1].z = fmaf(a1, w.z, acc[1].z); acc[1].w = fmaf(a1, w.w, acc[1].w);
        acc[2].x = fmaf(a2, w.x, acc[2].x); acc[2].y = fmaf(a2, w.y, acc[2].y);
        acc[2].z = fmaf(a2, w.z, acc[2].z); acc[2].w = fmaf(a2, w.w, acc[2].w);
        acc[3].x = fmaf(a3, w.x, acc[3].x); acc[3].y = fmaf(a3, w.y, acc[3].y);
        acc[3].z = fmaf(a3, w.z, acc[3].z); acc[3].w = fmaf(a3, w.w, acc[3].w);
        acc2[0].x = fmaf(a0, w2.x, acc2[0].x); acc2[0].y = fmaf(a0, w2.y, acc2[0].y);
        acc2[0].z = fmaf(a0, w2.z, acc2[0].z); acc2[0].w = fmaf(a0, w2.w, acc2[0].w);
        acc2[1].x = fmaf(a1, w2.x, acc2[1].x); acc2[1].y = fmaf(a1, w2.y, acc2[1].y);
        acc2[1].z = fmaf(a1, w2.z, acc2[1].z); acc2[1].w = fmaf(a1, w2.w, acc2[1].w);
        acc2[2].x = fmaf(a2, w2.x, acc2[2].x); acc2[2].y = fmaf(a2, w2.y, acc2[2].y);
        acc2[2].z = fmaf(a2, w2.z, acc2[2].z); acc2[2].w = fmaf(a2, w2.w, acc2[2].w);
        acc2[3].x = fmaf(a3, w2.x, acc2[3].x); acc2[3].y = fmaf(a3, w2.y, acc2[3].y);
        acc2[3].z = fmaf(a3, w2.z, acc2[3].z); acc2[3].w = fmaf(a3, w2.w, acc2[3].w);
    }

    #pragma unroll
    for (int r = 0; r < 4; r++) {
        int row = base + rowq * 4 + r;
        if (row < n) {
            float s = disq[row];
            float4 o;
            o.x = acc[r].x * s; o.y = acc[r].y * s;
            o.z = acc[r].z * s; o.w = acc[r].w * s;
            ((ushort4*)C16)[(size_t)row * 16 + (tid & 15)] = f4h(o);
            if (jk_mode == 1) {
                ((ushort4*)jkacc16)[(size_t)row * 16 + (tid & 15)] = f4h(acc2[r]);
            } else {
                float4 p = h4f(((const ushort4*)jkacc16)[(size_t)row * 16 + (tid & 15)]);
                p.x += acc2[r].x; p.y += acc2[r].y;
                p.z += acc2[r].z; p.w += acc2[r].w;
                ((ushort4*)jkacc16)[(size_t)row * 16 + (tid & 15)] = f4h(p);
            }
        }
    }
}

// ============ gather: wave per node, fp16 in/out, 8B loads, 4 edge slots (R12-verified) ============
__global__ __launch_bounds__(256) void k_gather(
    const int* __restrict__ rowptr, const int* __restrict__ csr,
    const unsigned short* __restrict__ hW16, const float* __restrict__ disq,
    const float* __restrict__ bias, unsigned short* __restrict__ hout16, int n)
{
    const ushort4* hW4 = (const ushort4*)hW16;
    int wid  = (blockIdx.x * 256 + threadIdx.x) >> 6;
    if (wid >= n) return;
    int lane = threadIdx.x & 63;
    int fb = lane & 15;
    int es = lane >> 4;
    int j  = rowptr[wid];
    int r1 = rowptr[wid + 1];
    float4 v  = make_float4(0.f, 0.f, 0.f, 0.f);
    float4 v2 = make_float4(0.f, 0.f, 0.f, 0.f);
    if (es == 0) v = h4f(hW4[(size_t)wid * 16 + fb]);    // self-loop
    while (j < r1) {
        int cnt = min(r1 - j, 64);
        int idx = (lane < cnt) ? csr[j + lane] : 0;
        for (int jj = 0; jj < cnt; jj += 16) {
            int i0 = jj + es, i1 = jj + 4 + es, i2 = jj + 8 + es, i3 = jj + 12 + es;
            int s0 = __shfl(idx, i0 & 63);
            int s1 = __shfl(idx, i1 & 63);
            int s2 = __shfl(idx, i2 & 63);
            int s3 = __shfl(idx, i3 & 63);
            float4 t0 = h4f(hW4[(size_t)s0 * 16 + fb]);
            float4 t1 = h4f(hW4[(size_t)s1 * 16 + fb]);
            float4 t2 = h4f(hW4[(size_t)s2 * 16 + fb]);
            float4 t3 = h4f(hW4[(size_t)s3 * 16 + fb]);
            if (i0 < cnt) { v.x  += t0.x; v.y  += t0.y; v.z  += t0.z; v.w  += t0.w; }
            if (i1 < cnt) { v2.x += t1.x; v2.y += t1.y; v2.z += t1.z; v2.w += t1.w; }
            if (i2 < cnt) { v.x  += t2.x; v.y  += t2.y; v.z  += t2.z; v.w  += t2.w; }
            if (i3 < cnt) { v2.x += t3.x; v2.y += t3.y; v2.z += t3.z; v2.w += t3.w; }
        }
        j += cnt;
    }
    v.x += v2.x; v.y += v2.y; v.z += v2.z; v.w += v2.w;
    v.x += __shfl_xor(v.x, 16); v.y += __shfl_xor(v.y, 16);
    v.z += __shfl_xor(v.z, 16); v.w += __shfl_xor(v.w, 16);
    v.x += __shfl_xor(v.x, 32); v.y += __shfl_xor(v.y, 32);
    v.z += __shfl_xor(v.z, 32); v.w += __shfl_xor(v.w, 32);
    if (es == 0) {
        float s = disq[wid];
        float4 b = ((const float4*)bias)[fb];
        float4 o;
        o.x = fmaxf(fmaf(s, v.x, b.x), 0.f);
        o.y = fmaxf(fmaf(s, v.y, b.y), 0.f);
        o.z = fmaxf(fmaf(s, v.z, b.z), 0.f);
        o.w = fmaxf(fmaf(s, v.w, b.w), 0.f);
        ((ushort4*)hout16)[(size_t)wid * 16 + fb] = f4h(o);
    }
}

// ============ final: t = relu(h@jkW5 + jkacc + jkb); pool by batch ============
__global__ __launch_bounds__(256) void k_jkfin_pool(
    const unsigned short* __restrict__ A16,
    const float* __restrict__ W,
    const unsigned short* __restrict__ jkacc16,
    const float* __restrict__ bias,
    const int* __restrict__ batch,
    float* __restrict__ pooled,
    int n)
{
    __shared__ float Ws[64 * 64];
    __shared__ float As[64 * 68];
    const int tid  = threadIdx.x;
    const int col4 = (tid & 15) * 4;
    const int rowq = tid >> 4;
    const int base = blockIdx.x * 64;

    #pragma unroll
    for (int i = 0; i < 4; i++) {
        float4 v = *(const float4*)(W + (size_t)(i * 256 + tid) * 4);
        *(float4*)(Ws + (size_t)(i * 256 + tid) * 4) = v;
    }
    {
        const ushort4* Ah = (const ushort4*)A16;
        #pragma unroll
        for (int rr = 0; rr < 4; rr++) {
            int row = base + rowq + rr * 16;
            float4 v = make_float4(0.f, 0.f, 0.f, 0.f);
            if (row < n) v = h4f(Ah[(size_t)row * 16 + (tid & 15)]);
            *(float4*)(As + (size_t)(rowq + rr * 16) * 68 + col4) = v;
        }
    }
    __syncthreads();

    float4 acc[4];
    #pragma unroll
    for (int r = 0; r < 4; r++) acc[r] = make_float4(0.f, 0.f, 0.f, 0.f);
    #pragma unroll 8
    for (int k = 0; k < 64; k++) {
        float4 w = *(const float4*)(Ws + k * 64 + col4);
        float a0 = As[(rowq * 4 + 0) * 68 + k];
        float a1 = As[(rowq * 4 + 1) * 68 + k];
        float a2 = As[(rowq * 4 + 2) * 68 + k];
        float a3 = As[(rowq * 4 + 3) * 68 + k];
        acc[0].x = fmaf(a0, w.x, acc[0].x); acc[0].y = fmaf(a0, w.y, acc[0].y);
        acc[0].z = fmaf(a0, w.z, acc[0].z); acc[0].w = fmaf(a0, w.w, acc[0].w);
        acc[1].x = fmaf(a1, w.x, acc[1].x); acc[1].y = fmaf(a1, w.y, acc[1].y);
        acc[1].z = fmaf(a1, w.z, acc[1].z); acc[1].w = fmaf(a1, w.w, acc[1].w);
        acc[2].x = fmaf(a2, w.x, acc[2].x); acc[2].y = fmaf(a2, w.y, acc[2].y);
        acc[2].z = fmaf(a2, w.z, acc[2].z); acc[2].w = fmaf(a2, w.w, acc[2].w);
        acc[3].x = fmaf(a3, w.x, acc[3].x); acc[3].y = fmaf(a3, w.y, acc[3].y);
        acc[3].z = fmaf(a3, w.z, acc[3].z); acc[3].w = fmaf(a3, w.w, acc[3].w);
    }
    __syncthreads();

    float* slab = Ws;
    #pragma unroll
    for (int i = tid; i < 4096; i += 256) slab[i] = 0.f;
    __syncthreads();

    float4 bb = *(const float4*)(bias + col4);
    int curg = -1;
    float4 s4 = make_float4(0.f, 0.f, 0.f, 0.f);
    #pragma unroll
    for (int r = 0; r < 4; r++) {
        int row = base + rowq * 4 + r;
        if (row < n) {
            float4 p = h4f(((const ushort4*)jkacc16)[(size_t)row * 16 + (tid & 15)]);
            float4 vv;
            vv.x = fmaxf(acc[r].x + p.x + bb.x, 0.f);
            vv.y = fmaxf(acc[r].y + p.y + bb.y, 0.f);
            vv.z = fmaxf(acc[r].z + p.z + bb.z, 0.f);
            vv.w = fmaxf(acc[r].w + p.w + bb.w, 0.f);
            int g = batch[row];
            if (g != curg) {
                if (curg >= 0) {
                    atomicAdd(&slab[curg * 64 + col4 + 0], s4.x);
                    atomicAdd(&slab[curg * 64 + col4 + 1], s4.y);
                    atomicAdd(&slab[curg * 64 + col4 + 2], s4.z);
                    atomicAdd(&slab[curg * 64 + col4 + 3], s4.w);
                }
                curg = g; s4 = vv;
            } else {
                s4.x += vv.x; s4.y += vv.y; s4.z += vv.z; s4.w += vv.w;
            }
        }
    }
    if (curg >= 0) {
        atomicAdd(&slab[curg * 64 + col4 + 0], s4.x);
        atomicAdd(&slab[curg * 64 + col4 + 1], s4.y);
        atomicAdd(&slab[curg * 64 + col4 + 2], s4.z);
        atomicAdd(&slab[curg * 64 + col4 + 3], s4.w);
    }
    __syncthreads();

    int g0 = batch[base];
    int g1 = batch[(base + 63 < n) ? (base + 63) : (n - 1)];
    int cnt = (g1 - g0 + 1) * 64;
    for (int i = tid; i < cnt; i += 256) {
        int g = g0 + (i >> 6);
        int c = i & 63;
        float v = slab[g * 64 + c];
        if (v != 0.f) atomicAdd(&pooled[g * 64 + c], v);
    }
}

// ============ head ============
__global__ __launch_bounds__(64) void k_head(
    const float* __restrict__ pooled,
    const float* __restrict__ W1, const float* __restrict__ b1,
    const float* __restrict__ W2, const float* __restrict__ b2,
    float* __restrict__ out)
{
    __shared__ float p[64];
    __shared__ float h1[64];
    __shared__ float lg[16];
    const int g = blockIdx.x;
    const int t = threadIdx.x;

    p[t] = pooled[g * 64 + t];
    __syncthreads();

    float acc = b1[t];
    #pragma unroll 8
    for (int k = 0; k < 64; k++) acc = fmaf(p[k], W1[k * 64 + t], acc);
    h1[t] = fmaxf(acc, 0.f);
    __syncthreads();

    if (t < NCLS) {
        float a = b2[t];
        #pragma unroll 8
        for (int j = 0; j < 64; j++) a = fmaf(h1[j], W2[j * NCLS + t], a);
        lg[t] = a;
    }
    __syncthreads();

    if (t == 0) {
        float mx = lg[0];
        #pragma unroll
        for (int c = 1; c < NCLS; c++) mx = fmaxf(mx, lg[c]);
        float ssum = 0.f;
        float e[NCLS];
        #pragma unroll
        for (int c = 0; c < NCLS; c++) { e[c] = __expf(lg[c] - mx); ssum += e[c]; }
        float inv = 1.0f / ssum;
        #pragma unroll
        for (int c = 0; c < NCLS; c++) out[g * NCLS + c] = e[c] * inv;
    }
}

extern "C" void kernel_launch(void* const* d_in, const int* in_sizes, int n_in,
                              void* d_out, int out_size, void* d_ws, size_t ws_size,
                              hipStream_t stream) {
    (void)in_sizes; (void)n_in; (void)out_size; (void)ws_size;
    const float* x     = (const float*)d_in[0];
    const int*   ei    = (const int*)d_in[1];
    const int*   batch = (const int*)d_in[2];
    const float* W0    = (const float*)d_in[3];
    const float* b0    = (const float*)d_in[4];
    const float* Wh    = (const float*)d_in[5];
    const float* bh    = (const float*)d_in[6];
    const float* jkW   = (const float*)d_in[7];
    const float* jkb   = (const float*)d_in[8];
    const float* W1    = (const float*)d_in[9];
    const float* b1    = (const float*)d_in[10];
    const float* W2    = (const float*)d_in[11];
    const float* b2    = (const float*)d_in[12];

    const int* src = ei;
    const int* dst = ei + NE;

    float*          fws     = (float*)d_ws;
    float*          disq    = fws;
    unsigned short* hWb     = (unsigned short*)(disq + 100352);
    unsigned short* h16     = hWb + (size_t)NN * 64;
    unsigned short* jkacc16 = h16 + (size_t)NN * 64;
    float*          pooled  = (float*)(jkacc16 + (size_t)NN * 64);
    int*            counts  = (int*)(pooled + 4096);
    int*            rowptr  = counts + 100352;
    int*            wptr    = rowptr + 100352;
    int*            bsum    = wptr + 100352;
    int*            csr     = bsum + 512;

    const int NB_N = (NN + 255) / 256;

    hipMemsetAsync(counts, 0, (size_t)NN * sizeof(int), stream);
    k_hist<<<(NE + 1023) / 1024, 256, 0, stream>>>(dst, counts, NE);
    k_blocksum<<<NB_N, 256, 0, stream>>>(counts, bsum, NN);
    k_scanbsum<<<1, 512, 0, stream>>>(bsum, NB_N);
    k_scanwrite<<<NB_N, 256, 0, stream>>>(counts, bsum, rowptr, wptr, disq, NN, NE);

    // fused: GEMM blocks first, scatter behind
    k_scatter_gemm0<<<GEMM_GRID + SCAT_BLKS, 256, 0, stream>>>(
        src, dst, wptr, csr, NE, x, W0, disq, hWb, NN);

    const int gather_grid = (NN + 3) / 4;
    k_gather<<<gather_grid, 256, 0, stream>>>(rowptr, csr, hWb, disq, b0, h16, NN);
    for (int l = 1; l < NLAY; l++) {
        const float* W   = Wh + (size_t)(l - 1) * 64 * 64;
        const float* jw  = jkW + (size_t)(l - 1) * 64 * 64;
        int          jkm = (l == 1) ? 1 : 2;
        k_gemm_dual<<<GEMM_GRID, 256, 0, stream>>>(h16, W, jw, disq, hWb, jkacc16, jkm, NN);
        k_gather<<<gather_grid, 256, 0, stream>>>(rowptr, csr, hWb, disq,
                                                  bh + (size_t)(l - 1) * 64, h16, NN);
    }

    hipMemsetAsync(pooled, 0, 64 * 64 * sizeof(float), stream);
    k_jkfin_pool<<<GEMM_GRID, 256, 0, stream>>>(h16, jkW + (size_t)5 * 64 * 64, jkacc16,
                                                jkb, batch, pooled, NN);
    k_head<<<NGRAPH, 64, 0, stream>>>(pooled, W1, b1, W2, b2, (float*)d_out);
}

// Round 16
// 496.663 us; speedup vs baseline: 1.5678x; 1.0496x over previous
//
#include <hip/hip_runtime.h>
#include <hip/hip_fp16.h>

#define NN 100000
#define NE 1000000
#define F_INF 128
#define HID 64
#define NLAY 6
#define NCLS 10
#define NGRAPH 64
#define PART_SZ 12500   // NN/8 — contiguous node range per XCD partition
#define SCAT_BLKS (((NE + 2047) / 2048) * 8)   // 489*8 = 3912
#define GEMM_GRID ((NN + 63) / 64)             // 1563

typedef float floatx2 __attribute__((ext_vector_type(2)));

__device__ __forceinline__ float4 h4f(ushort4 u) {
    __half2 lo = *reinterpret_cast<__half2*>(&u);
    __half2 hi = *reinterpret_cast<__half2*>(reinterpret_cast<unsigned short*>(&u) + 2);
    float2 a = __half22float2(lo);
    float2 b = __half22float2(hi);
    return make_float4(a.x, a.y, b.x, b.y);
}

__device__ __forceinline__ ushort4 f4h(float4 v) {
    __half2 lo = __floats2half2_rn(v.x, v.y);
    __half2 hi = __floats2half2_rn(v.z, v.w);
    ushort4 u;
    *reinterpret_cast<__half2*>(&u) = lo;
    *reinterpret_cast<__half2*>(reinterpret_cast<unsigned short*>(&u) + 2) = hi;
    return u;
}

// fp8 (e4m3 ocp on gfx950) pack/unpack — roundtrip through our own buffers only
__device__ __forceinline__ unsigned f4_fp8(float4 v) {
    unsigned w = 0;
    w = __builtin_amdgcn_cvt_pk_fp8_f32(v.x, v.y, w, false);
    w = __builtin_amdgcn_cvt_pk_fp8_f32(v.z, v.w, w, true);
    return w;
}

__device__ __forceinline__ void accf8(unsigned u, float4& a) {
    floatx2 lo = __builtin_amdgcn_cvt_pk_f32_fp8(u, false);
    floatx2 hi = __builtin_amdgcn_cvt_pk_f32_fp8(u, true);
    a.x += lo[0]; a.y += lo[1]; a.z += hi[0]; a.w += hi[1];
}

// ================= CSR build =================
__global__ void k_hist(const int* __restrict__ dst, int* __restrict__ counts, int e) {
    int i0 = blockIdx.x * 1024 + threadIdx.x;
    #pragma unroll
    for (int k = 0; k < 4; k++) {
        int i = i0 + k * 256;
        if (i < e) atomicAdd(&counts[dst[i]], 1);
    }
}

__global__ void k_blocksum(const int* __restrict__ counts, int* __restrict__ bsum, int n) {
    int i = blockIdx.x * 256 + threadIdx.x;
    int v = (i < n) ? counts[i] : 0;
    #pragma unroll
    for (int off = 32; off >= 1; off >>= 1) v += __shfl_down(v, off);
    __shared__ int ws[4];
    if ((threadIdx.x & 63) == 0) ws[threadIdx.x >> 6] = v;
    __syncthreads();
    if (threadIdx.x == 0) bsum[blockIdx.x] = ws[0] + ws[1] + ws[2] + ws[3];
}

__global__ void k_scanbsum(int* __restrict__ bsum, int nb) {   // 1 block, 512 thr
    __shared__ int sh[512];
    int t = threadIdx.x;
    int v = (t < nb) ? bsum[t] : 0;
    sh[t] = v; __syncthreads();
    for (int off = 1; off < 512; off <<= 1) {
        int x = (t >= off) ? sh[t - off] : 0;
        __syncthreads();
        sh[t] += x; __syncthreads();
    }
    if (t < nb) bsum[t] = sh[t] - v;   // exclusive
}

__global__ void k_scanwrite(const int* __restrict__ counts, const int* __restrict__ bsumx,
                            int* __restrict__ rowptr, int* __restrict__ wptr,
                            float* __restrict__ disq, int n, int e) {
    __shared__ int sh[256];
    int t = threadIdx.x;
    int i = blockIdx.x * 256 + t;
    int v = (i < n) ? counts[i] : 0;
    sh[t] = v; __syncthreads();
    for (int off = 1; off < 256; off <<= 1) {
        int x = (t >= off) ? sh[t - off] : 0;
        __syncthreads();
        sh[t] += x; __syncthreads();
    }
    int excl = sh[t] - v + bsumx[blockIdx.x];
    if (i < n) {
        rowptr[i] = excl;
        wptr[i]   = excl;
        disq[i]   = rsqrtf((float)(v + 1));   // +1 self-loop
    }
    if (i == 0) rowptr[n] = e;
}

// ============ fused: layer-0 GEMM (blocks FIRST) + XCD-partitioned scatter ============
__global__ __launch_bounds__(256) void k_scatter_gemm0(
    const int* __restrict__ src, const int* __restrict__ dst,
    int* __restrict__ wptr, int* __restrict__ csr, int e,
    const float* __restrict__ x, const float* __restrict__ W0,
    const float* __restrict__ disq, unsigned* __restrict__ C8, int n)
{
    __shared__ float Ws[32 * 64];    // 8KB
    __shared__ float As[64 * 36];    // 9.2KB

    if (blockIdx.x >= GEMM_GRID) {
        // ---- scatter ----
        int sbid = blockIdx.x - GEMM_GRID;
        int part = sbid & 7;
        int i0 = (sbid >> 3) * 2048 + threadIdx.x;
        #pragma unroll
        for (int k = 0; k < 8; k++) {
            int i = i0 + k * 256;
            if (i < e) {
                int d = dst[i];
                if (d / PART_SZ == part) {
                    int pos = atomicAdd(&wptr[d], 1);
                    csr[pos] = src[i];
                }
            }
        }
        return;
    }

    // ---- layer-0 GEMM, K-chunk=32 ----
    const int tid  = threadIdx.x;
    const int col4 = (tid & 15) * 4;
    const int rowq = tid >> 4;
    const int base = blockIdx.x * 64;
    const int ar   = tid >> 3;
    const int ac4  = (tid & 7) * 4;

    float4 wreg[2], areg[2];
    #pragma unroll
    for (int i = 0; i < 2; i++)
        wreg[i] = *(const float4*)(W0 + (size_t)(i * 256 + tid) * 4);
    #pragma unroll
    for (int rr = 0; rr < 2; rr++) {
        int row = base + ar + rr * 32;
        areg[rr] = make_float4(0.f, 0.f, 0.f, 0.f);
        if (row < n) areg[rr] = *(const float4*)(x + (size_t)row * F_INF + ac4);
    }
    #pragma unroll
    for (int i = 0; i < 2; i++)
        *(float4*)(Ws + (size_t)(i * 256 + tid) * 4) = wreg[i];
    #pragma unroll
    for (int rr = 0; rr < 2; rr++)
        *(float4*)(As + (size_t)(ar + rr * 32) * 36 + ac4) = areg[rr];
    __syncthreads();

    float4 acc[4];
    #pragma unroll
    for (int r = 0; r < 4; r++) acc[r] = make_float4(0.f, 0.f, 0.f, 0.f);

    for (int k0 = 0; k0 < F_INF; k0 += 32) {
        const bool more = (k0 + 32) < F_INF;
        if (more) {
            #pragma unroll
            for (int i = 0; i < 2; i++)
                wreg[i] = *(const float4*)(W0 + (size_t)(k0 + 32) * 64 + (i * 256 + tid) * 4);
            #pragma unroll
            for (int rr = 0; rr < 2; rr++) {
                int row = base + ar + rr * 32;
                areg[rr] = make_float4(0.f, 0.f, 0.f, 0.f);
                if (row < n) areg[rr] = *(const float4*)(x + (size_t)row * F_INF + k0 + 32 + ac4);
            }
        }
        #pragma unroll 8
        for (int k = 0; k < 32; k++) {
            float4 w = *(const float4*)(Ws + k * 64 + col4);
            float a0 = As[(rowq * 4 + 0) * 36 + k];
            float a1 = As[(rowq * 4 + 1) * 36 + k];
            float a2 = As[(rowq * 4 + 2) * 36 + k];
            float a3 = As[(rowq * 4 + 3) * 36 + k];
            acc[0].x = fmaf(a0, w.x, acc[0].x); acc[0].y = fmaf(a0, w.y, acc[0].y);
            acc[0].z = fmaf(a0, w.z, acc[0].z); acc[0].w = fmaf(a0, w.w, acc[0].w);
            acc[1].x = fmaf(a1, w.x, acc[1].x); acc[1].y = fmaf(a1, w.y, acc[1].y);
            acc[1].z = fmaf(a1, w.z, acc[1].z); acc[1].w = fmaf(a1, w.w, acc[1].w);
            acc[2].x = fmaf(a2, w.x, acc[2].x); acc[2].y = fmaf(a2, w.y, acc[2].y);
            acc[2].z = fmaf(a2, w.z, acc[2].z); acc[2].w = fmaf(a2, w.w, acc[2].w);
            acc[3].x = fmaf(a3, w.x, acc[3].x); acc[3].y = fmaf(a3, w.y, acc[3].y);
            acc[3].z = fmaf(a3, w.z, acc[3].z); acc[3].w = fmaf(a3, w.w, acc[3].w);
        }
        __syncthreads();
        if (more) {
            #pragma unroll
            for (int i = 0; i < 2; i++)
                *(float4*)(Ws + (size_t)(i * 256 + tid) * 4) = wreg[i];
            #pragma unroll
            for (int rr = 0; rr < 2; rr++)
                *(float4*)(As + (size_t)(ar + rr * 32) * 36 + ac4) = areg[rr];
            __syncthreads();
        }
    }

    #pragma unroll
    for (int r = 0; r < 4; r++) {
        int row = base + rowq * 4 + r;
        if (row < n) {
            float s = disq[row];
            float4 o;
            o.x = acc[r].x * s; o.y = acc[r].y * s;
            o.z = acc[r].z * s; o.w = acc[r].w * s;
            C8[(size_t)row * 16 + (tid & 15)] = f4_fp8(o);
        }
    }
}

// ============ dual GEMM layers 1-5 (K=64, fp16 A): C fp8, jkacc fp16 ============
__global__ __launch_bounds__(256) void k_gemm_dual(
    const unsigned short* __restrict__ A16,
    const float* __restrict__ W,
    const float* __restrict__ jkw,
    const float* __restrict__ disq,
    unsigned* __restrict__ C8,
    unsigned short* __restrict__ jkacc16,
    int jk_mode, int n)
{
    __shared__ float Ws[64 * 64];
    __shared__ float Ws2[64 * 64];
    __shared__ float As[64 * 68];
    const int tid  = threadIdx.x;
    const int col4 = (tid & 15) * 4;
    const int rowq = tid >> 4;
    const int base = blockIdx.x * 64;

    #pragma unroll
    for (int i = 0; i < 4; i++) {
        float4 v = *(const float4*)(W + (size_t)(i * 256 + tid) * 4);
        *(float4*)(Ws + (size_t)(i * 256 + tid) * 4) = v;
        float4 v2 = *(const float4*)(jkw + (size_t)(i * 256 + tid) * 4);
        *(float4*)(Ws2 + (size_t)(i * 256 + tid) * 4) = v2;
    }
    {
        const ushort4* Ah = (const ushort4*)A16;
        #pragma unroll
        for (int rr = 0; rr < 4; rr++) {
            int row = base + rowq + rr * 16;
            float4 v = make_float4(0.f, 0.f, 0.f, 0.f);
            if (row < n) v = h4f(Ah[(size_t)row * 16 + (tid & 15)]);
            *(float4*)(As + (size_t)(rowq + rr * 16) * 68 + col4) = v;
        }
    }
    __syncthreads();

    float4 acc[4], acc2[4];
    #pragma unroll
    for (int r = 0; r < 4; r++) {
        acc[r]  = make_float4(0.f, 0.f, 0.f, 0.f);
        acc2[r] = make_float4(0.f, 0.f, 0.f, 0.f);
    }

    #pragma unroll 4
    for (int k = 0; k < 64; k++) {
        float4 w  = *(const float4*)(Ws  + k * 64 + col4);
        float4 w2 = *(const float4*)(Ws2 + k * 64 + col4);
        float a0 = As[(rowq * 4 + 0) * 68 + k];
        float a1 = As[(rowq * 4 + 1) * 68 + k];
        float a2 = As[(rowq * 4 + 2) * 68 + k];
        float a3 = As[(rowq * 4 + 3) * 68 + k];
        acc[0].x = fmaf(a0, w.x, acc[0].x); acc[0].y = fmaf(a0, w.y, acc[0].y);
        acc[0].z = fmaf(a0, w.z, acc[0].z); acc[0].w = fmaf(a0, w.w, acc[0].w);
        acc[1].x = fmaf(a1, w.x, acc[1].x); acc[1].y = fmaf(a1, w.y, acc[1].y);
        acc[1].z = fmaf(a1, w.z, acc[1].z); acc[1].w = fmaf(a1, w.w, acc[1].w);
        acc[2].x = fmaf(a2, w.x, acc[2].x); acc[2].y = fmaf(a2, w.y, acc[2].y);
        acc[2].z = fmaf(a2, w.z, acc[2].z); acc[2].w = fmaf(a2, w.w, acc[2].w);
        acc[3].x = fmaf(a3, w.x, acc[3].x); acc[3].y = fmaf(a3, w.y, acc[3].y);
        acc[3].z = fmaf(a3, w.z, acc[3].z); acc[3].w = fmaf(a3, w.w, acc[3].w);
        acc2[0].x = fmaf(a0, w2.x, acc2[0].x); acc2[0].y = fmaf(a0, w2.y, acc2[0].y);
        acc2[0].z = fmaf(a0, w2.z, acc2[0].z); acc2[0].w = fmaf(a0, w2.w, acc2[0].w);
        acc2[1].x = fmaf(a1, w2.x, acc2[1].x); acc2[1].y = fmaf(a1, w2.y, acc2[1].y);
        acc2[1].z = fmaf(a1, w2.z, acc2[1].z); acc2[1].w = fmaf(a1, w2.w, acc2[1].w);
        acc2[2].x = fmaf(a2, w2.x, acc2[2].x); acc2[2].y = fmaf(a2, w2.y, acc2[2].y);
        acc2[2].z = fmaf(a2, w2.z, acc2[2].z); acc2[2].w = fmaf(a2, w2.w, acc2[2].w);
        acc2[3].x = fmaf(a3, w2.x, acc2[3].x); acc2[3].y = fmaf(a3, w2.y, acc2[3].y);
        acc2[3].z = fmaf(a3, w2.z, acc2[3].z); acc2[3].w = fmaf(a3, w2.w, acc2[3].w);
    }

    #pragma unroll
    for (int r = 0; r < 4; r++) {
        int row = base + rowq * 4 + r;
        if (row < n) {
            float s = disq[row];
            float4 o;
            o.x = acc[r].x * s; o.y = acc[r].y * s;
            o.z = acc[r].z * s; o.w = acc[r].w * s;
            C8[(size_t)row * 16 + (tid & 15)] = f4_fp8(o);
            if (jk_mode == 1) {
                ((ushort4*)jkacc16)[(size_t)row * 16 + (tid & 15)] = f4h(acc2[r]);
            } else {
                float4 p = h4f(((const ushort4*)jkacc16)[(size_t)row * 16 + (tid & 15)]);
                p.x += acc2[r].x; p.y += acc2[r].y;
                p.z += acc2[r].z; p.w += acc2[r].w;
                ((ushort4*)jkacc16)[(size_t)row * 16 + (tid & 15)] = f4h(p);
            }
        }
    }
}

// ============ gather: wave per node, fp8 in (64B row = 1 line/edge), fp16 out ============
__global__ __launch_bounds__(256) void k_gather(
    const int* __restrict__ rowptr, const int* __restrict__ csr,
    const unsigned* __restrict__ hW8, const float* __restrict__ disq,
    const float* __restrict__ bias, unsigned short* __restrict__ hout16, int n)
{
    int wid  = (blockIdx.x * 256 + threadIdx.x) >> 6;
    if (wid >= n) return;
    int lane = threadIdx.x & 63;
    int fb = lane & 15;       // 4B chunk index within 64B row (4 features)
    int es = lane >> 4;       // edge slot 0..3
    int j  = rowptr[wid];
    int r1 = rowptr[wid + 1];
    float4 v  = make_float4(0.f, 0.f, 0.f, 0.f);
    float4 v2 = make_float4(0.f, 0.f, 0.f, 0.f);
    if (es == 0) accf8(hW8[(size_t)wid * 16 + fb], v);   // self-loop
    while (j < r1) {
        int cnt = min(r1 - j, 64);
        int idx = (lane < cnt) ? csr[j + lane] : 0;
        for (int jj = 0; jj < cnt; jj += 16) {
            int i0 = jj + es, i1 = jj + 4 + es, i2 = jj + 8 + es, i3 = jj + 12 + es;
            int s0 = __shfl(idx, i0 & 63);
            int s1 = __shfl(idx, i1 & 63);
            int s2 = __shfl(idx, i2 & 63);
            int s3 = __shfl(idx, i3 & 63);
            unsigned t0 = hW8[(size_t)s0 * 16 + fb];
            unsigned t1 = hW8[(size_t)s1 * 16 + fb];
            unsigned t2 = hW8[(size_t)s2 * 16 + fb];
            unsigned t3 = hW8[(size_t)s3 * 16 + fb];
            if (i0 < cnt) accf8(t0, v);
            if (i1 < cnt) accf8(t1, v2);
            if (i2 < cnt) accf8(t2, v);
            if (i3 < cnt) accf8(t3, v2);
        }
        j += cnt;
    }
    v.x += v2.x; v.y += v2.y; v.z += v2.z; v.w += v2.w;
    v.x += __shfl_xor(v.x, 16); v.y += __shfl_xor(v.y, 16);
    v.z += __shfl_xor(v.z, 16); v.w += __shfl_xor(v.w, 16);
    v.x += __shfl_xor(v.x, 32); v.y += __shfl_xor(v.y, 32);
    v.z += __shfl_xor(v.z, 32); v.w += __shfl_xor(v.w, 32);
    if (es == 0) {
        float s = disq[wid];
        float4 b = ((const float4*)bias)[fb];
        float4 o;
        o.x = fmaxf(fmaf(s, v.x, b.x), 0.f);
        o.y = fmaxf(fmaf(s, v.y, b.y), 0.f);
        o.z = fmaxf(fmaf(s, v.z, b.z), 0.f);
        o.w = fmaxf(fmaf(s, v.w, b.w), 0.f);
        ((ushort4*)hout16)[(size_t)wid * 16 + fb] = f4h(o);
    }
}

// ============ final: t = relu(h@jkW5 + jkacc + jkb); pool by batch ============
__global__ __launch_bounds__(256) void k_jkfin_pool(
    const unsigned short* __restrict__ A16,
    const float* __restrict__ W,
    const unsigned short* __restrict__ jkacc16,
    const float* __restrict__ bias,
    const int* __restrict__ batch,
    float* __restrict__ pooled,
    int n)
{
    __shared__ float Ws[64 * 64];
    __shared__ float As[64 * 68];
    const int tid  = threadIdx.x;
    const int col4 = (tid & 15) * 4;
    const int rowq = tid >> 4;
    const int base = blockIdx.x * 64;

    #pragma unroll
    for (int i = 0; i < 4; i++) {
        float4 v = *(const float4*)(W + (size_t)(i * 256 + tid) * 4);
        *(float4*)(Ws + (size_t)(i * 256 + tid) * 4) = v;
    }
    {
        const ushort4* Ah = (const ushort4*)A16;
        #pragma unroll
        for (int rr = 0; rr < 4; rr++) {
            int row = base + rowq + rr * 16;
            float4 v = make_float4(0.f, 0.f, 0.f, 0.f);
            if (row < n) v = h4f(Ah[(size_t)row * 16 + (tid & 15)]);
            *(float4*)(As + (size_t)(rowq + rr * 16) * 68 + col4) = v;
        }
    }
    __syncthreads();

    float4 acc[4];
    #pragma unroll
    for (int r = 0; r < 4; r++) acc[r] = make_float4(0.f, 0.f, 0.f, 0.f);
    #pragma unroll 8
    for (int k = 0; k < 64; k++) {
        float4 w = *(const float4*)(Ws + k * 64 + col4);
        float a0 = As[(rowq * 4 + 0) * 68 + k];
        float a1 = As[(rowq * 4 + 1) * 68 + k];
        float a2 = As[(rowq * 4 + 2) * 68 + k];
        float a3 = As[(rowq * 4 + 3) * 68 + k];
        acc[0].x = fmaf(a0, w.x, acc[0].x); acc[0].y = fmaf(a0, w.y, acc[0].y);
        acc[0].z = fmaf(a0, w.z, acc[0].z); acc[0].w = fmaf(a0, w.w, acc[0].w);
        acc[1].x = fmaf(a1, w.x, acc[1].x); acc[1].y = fmaf(a1, w.y, acc[1].y);
        acc[1].z = fmaf(a1, w.z, acc[1].z); acc[1].w = fmaf(a1, w.w, acc[1].w);
        acc[2].x = fmaf(a2, w.x, acc[2].x); acc[2].y = fmaf(a2, w.y, acc[2].y);
        acc[2].z = fmaf(a2, w.z, acc[2].z); acc[2].w = fmaf(a2, w.w, acc[2].w);
        acc[3].x = fmaf(a3, w.x, acc[3].x); acc[3].y = fmaf(a3, w.y, acc[3].y);
        acc[3].z = fmaf(a3, w.z, acc[3].z); acc[3].w = fmaf(a3, w.w, acc[3].w);
    }
    __syncthreads();

    float* slab = Ws;
    #pragma unroll
    for (int i = tid; i < 4096; i += 256) slab[i] = 0.f;
    __syncthreads();

    float4 bb = *(const float4*)(bias + col4);
    int curg = -1;
    float4 s4 = make_float4(0.f, 0.f, 0.f, 0.f);
    #pragma unroll
    for (int r = 0; r < 4; r++) {
        int row = base + rowq * 4 + r;
        if (row < n) {
            float4 p = h4f(((const ushort4*)jkacc16)[(size_t)row * 16 + (tid & 15)]);
            float4 vv;
            vv.x = fmaxf(acc[r].x + p.x + bb.x, 0.f);
            vv.y = fmaxf(acc[r].y + p.y + bb.y, 0.f);
            vv.z = fmaxf(acc[r].z + p.z + bb.z, 0.f);
            vv.w = fmaxf(acc[r].w + p.w + bb.w, 0.f);
            int g = batch[row];
            if (g != curg) {
                if (curg >= 0) {
                    atomicAdd(&slab[curg * 64 + col4 + 0], s4.x);
                    atomicAdd(&slab[curg * 64 + col4 + 1], s4.y);
                    atomicAdd(&slab[curg * 64 + col4 + 2], s4.z);
                    atomicAdd(&slab[curg * 64 + col4 + 3], s4.w);
                }
                curg = g; s4 = vv;
            } else {
                s4.x += vv.x; s4.y += vv.y; s4.z += vv.z; s4.w += vv.w;
            }
        }
    }
    if (curg >= 0) {
        atomicAdd(&slab[curg * 64 + col4 + 0], s4.x);
        atomicAdd(&slab[curg * 64 + col4 + 1], s4.y);
        atomicAdd(&slab[curg * 64 + col4 + 2], s4.z);
        atomicAdd(&slab[curg * 64 + col4 + 3], s4.w);
    }
    __syncthreads();

    int g0 = batch[base];
    int g1 = batch[(base + 63 < n) ? (base + 63) : (n - 1)];
    int cnt = (g1 - g0 + 1) * 64;
    for (int i = tid; i < cnt; i += 256) {
        int g = g0 + (i >> 6);
        int c = i & 63;
        float v = slab[g * 64 + c];
        if (v != 0.f) atomicAdd(&pooled[g * 64 + c], v);
    }
}

// ============ head ============
__global__ __launch_bounds__(64) void k_head(
    const float* __restrict__ pooled,
    const float* __restrict__ W1, const float* __restrict__ b1,
    const float* __restrict__ W2, const float* __restrict__ b2,
    float* __restrict__ out)
{
    __shared__ float p[64];
    __shared__ float h1[64];
    __shared__ float lg[16];
    const int g = blockIdx.x;
    const int t = threadIdx.x;

    p[t] = pooled[g * 64 + t];
    __syncthreads();

    float acc = b1[t];
    #pragma unroll 8
    for (int k = 0; k < 64; k++) acc = fmaf(p[k], W1[k * 64 + t], acc);
    h1[t] = fmaxf(acc, 0.f);
    __syncthreads();

    if (t < NCLS) {
        float a = b2[t];
        #pragma unroll 8
        for (int j = 0; j < 64; j++) a = fmaf(h1[j], W2[j * NCLS + t], a);
        lg[t] = a;
    }
    __syncthreads();

    if (t == 0) {
        float mx = lg[0];
        #pragma unroll
        for (int c = 1; c < NCLS; c++) mx = fmaxf(mx, lg[c]);
        float ssum = 0.f;
        float e[NCLS];
        #pragma unroll
        for (int c = 0; c < NCLS; c++) { e[c] = __expf(lg[c] - mx); ssum += e[c]; }
        float inv = 1.0f / ssum;
        #pragma unroll
        for (int c = 0; c < NCLS; c++) out[g * NCLS + c] = e[c] * inv;
    }
}

extern "C" void kernel_launch(void* const* d_in, const int* in_sizes, int n_in,
                              void* d_out, int out_size, void* d_ws, size_t ws_size,
                              hipStream_t stream) {
    (void)in_sizes; (void)n_in; (void)out_size; (void)ws_size;
    const float* x     = (const float*)d_in[0];
    const int*   ei    = (const int*)d_in[1];
    const int*   batch = (const int*)d_in[2];
    const float* W0    = (const float*)d_in[3];
    const float* b0    = (const float*)d_in[4];
    const float* Wh    = (const float*)d_in[5];
    const float* bh    = (const float*)d_in[6];
    const float* jkW   = (const float*)d_in[7];
    const float* jkb   = (const float*)d_in[8];
    const float* W1    = (const float*)d_in[9];
    const float* b1    = (const float*)d_in[10];
    const float* W2    = (const float*)d_in[11];
    const float* b2    = (const float*)d_in[12];

    const int* src = ei;
    const int* dst = ei + NE;

    float*          fws     = (float*)d_ws;
    float*          disq    = fws;                                   // 100352 f
    unsigned*       hWb8    = (unsigned*)(disq + 100352);            // NN*16 u32 (fp8 rows)
    unsigned short* h16     = (unsigned short*)(hWb8 + (size_t)NN * 16);  // NN*64 fp16
    unsigned short* jkacc16 = h16 + (size_t)NN * 64;                 // NN*64 fp16
    float*          pooled  = (float*)(jkacc16 + (size_t)NN * 64);   // 4096 f
    int*            counts  = (int*)(pooled + 4096);
    int*            rowptr  = counts + 100352;
    int*            wptr    = rowptr + 100352;
    int*            bsum    = wptr + 100352;
    int*            csr     = bsum + 512;

    const int NB_N = (NN + 255) / 256;

    hipMemsetAsync(counts, 0, (size_t)NN * sizeof(int), stream);
    k_hist<<<(NE + 1023) / 1024, 256, 0, stream>>>(dst, counts, NE);
    k_blocksum<<<NB_N, 256, 0, stream>>>(counts, bsum, NN);
    k_scanbsum<<<1, 512, 0, stream>>>(bsum, NB_N);
    k_scanwrite<<<NB_N, 256, 0, stream>>>(counts, bsum, rowptr, wptr, disq, NN, NE);

    // fused: GEMM blocks first, scatter behind
    k_scatter_gemm0<<<GEMM_GRID + SCAT_BLKS, 256, 0, stream>>>(
        src, dst, wptr, csr, NE, x, W0, disq, hWb8, NN);

    const int gather_grid = (NN + 3) / 4;
    k_gather<<<gather_grid, 256, 0, stream>>>(rowptr, csr, hWb8, disq, b0, h16, NN);
    for (int l = 1; l < NLAY; l++) {
        const float* W   = Wh + (size_t)(l - 1) * 64 * 64;
        const float* jw  = jkW + (size_t)(l - 1) * 64 * 64;
        int          jkm = (l == 1) ? 1 : 2;
        k_gemm_dual<<<GEMM_GRID, 256, 0, stream>>>(h16, W, jw, disq, hWb8, jkacc16, jkm, NN);
        k_gather<<<gather_grid, 256, 0, stream>>>(rowptr, csr, hWb8, disq,
                                                  bh + (size_t)(l - 1) * 64, h16, NN);
    }

    hipMemsetAsync(pooled, 0, 64 * 64 * sizeof(float), stream);
    k_jkfin_pool<<<GEMM_GRID, 256, 0, stream>>>(h16, jkW + (size_t)5 * 64 * 64, jkacc16,
                                                jkb, batch, pooled, NN);
    k_head<<<NGRAPH, 64, 0, stream>>>(pooled, W1, b1, W2, b2, (float*)d_out);
}

// Round 17
// 460.276 us; speedup vs baseline: 1.6918x; 1.0791x over previous
//
#include <hip/hip_runtime.h>
#include <hip/hip_fp16.h>

#define NN 100000
#define NE 1000000
#define F_INF 128
#define HID 64
#define NLAY 6
#define NCLS 10
#define NGRAPH 64
#define PART_SZ 12500   // NN/8 — contiguous node range per XCD partition
#define SCAT_BLKS (((NE + 2047) / 2048) * 8)   // 489*8 = 3912
#define GEMM_GRID ((NN + 63) / 64)             // 1563

typedef float floatx2 __attribute__((ext_vector_type(2)));
typedef short bf16x8 __attribute__((ext_vector_type(8)));
typedef float f32x4 __attribute__((ext_vector_type(4)));

__device__ __forceinline__ float4 h4f(ushort4 u) {
    __half2 lo = *reinterpret_cast<__half2*>(&u);
    __half2 hi = *reinterpret_cast<__half2*>(reinterpret_cast<unsigned short*>(&u) + 2);
    float2 a = __half22float2(lo);
    float2 b = __half22float2(hi);
    return make_float4(a.x, a.y, b.x, b.y);
}

__device__ __forceinline__ ushort4 f4h(float4 v) {
    __half2 lo = __floats2half2_rn(v.x, v.y);
    __half2 hi = __floats2half2_rn(v.z, v.w);
    ushort4 u;
    *reinterpret_cast<__half2*>(&u) = lo;
    *reinterpret_cast<__half2*>(reinterpret_cast<unsigned short*>(&u) + 2) = hi;
    return u;
}

// ---- bf16 helpers (RNE) ----
__device__ __forceinline__ unsigned short f2bf(float f) {
    unsigned u = __float_as_uint(f);
    u += 0x7FFF + ((u >> 16) & 1);
    return (unsigned short)(u >> 16);
}
__device__ __forceinline__ float bf2f(unsigned short h) {
    return __uint_as_float(((unsigned)h) << 16);
}
__device__ __forceinline__ ushort4 f4bf(float4 v) {
    ushort4 u;
    u.x = f2bf(v.x); u.y = f2bf(v.y); u.z = f2bf(v.z); u.w = f2bf(v.w);
    return u;
}
__device__ __forceinline__ float4 bf4f(ushort4 u) {
    return make_float4(bf2f(u.x), bf2f(u.y), bf2f(u.z), bf2f(u.w));
}

// fp8 (e4m3 ocp on gfx950) pack/unpack — roundtrip through our own buffers only
__device__ __forceinline__ unsigned f4_fp8(float4 v) {
    unsigned w = 0;
    w = __builtin_amdgcn_cvt_pk_fp8_f32(v.x, v.y, w, false);
    w = __builtin_amdgcn_cvt_pk_fp8_f32(v.z, v.w, w, true);
    return w;
}
__device__ __forceinline__ void accf8(unsigned u, float4& a) {
    floatx2 lo = __builtin_amdgcn_cvt_pk_f32_fp8(u, false);
    floatx2 hi = __builtin_amdgcn_cvt_pk_f32_fp8(u, true);
    a.x += lo[0]; a.y += lo[1]; a.z += hi[0]; a.w += hi[1];
}

// ================= CSR build =================
__global__ void k_hist(const int* __restrict__ dst, int* __restrict__ counts, int e) {
    int i0 = blockIdx.x * 1024 + threadIdx.x;
    #pragma unroll
    for (int k = 0; k < 4; k++) {
        int i = i0 + k * 256;
        if (i < e) atomicAdd(&counts[dst[i]], 1);
    }
}

__global__ void k_blocksum(const int* __restrict__ counts, int* __restrict__ bsum, int n) {
    int i = blockIdx.x * 256 + threadIdx.x;
    int v = (i < n) ? counts[i] : 0;
    #pragma unroll
    for (int off = 32; off >= 1; off >>= 1) v += __shfl_down(v, off);
    __shared__ int ws[4];
    if ((threadIdx.x & 63) == 0) ws[threadIdx.x >> 6] = v;
    __syncthreads();
    if (threadIdx.x == 0) bsum[blockIdx.x] = ws[0] + ws[1] + ws[2] + ws[3];
}

__global__ void k_scanbsum(int* __restrict__ bsum, int nb) {   // 1 block, 512 thr
    __shared__ int sh[512];
    int t = threadIdx.x;
    int v = (t < nb) ? bsum[t] : 0;
    sh[t] = v; __syncthreads();
    for (int off = 1; off < 512; off <<= 1) {
        int x = (t >= off) ? sh[t - off] : 0;
        __syncthreads();
        sh[t] += x; __syncthreads();
    }
    if (t < nb) bsum[t] = sh[t] - v;   // exclusive
}

__global__ void k_scanwrite(const int* __restrict__ counts, const int* __restrict__ bsumx,
                            int* __restrict__ rowptr, int* __restrict__ wptr,
                            float* __restrict__ disq, int n, int e) {
    __shared__ int sh[256];
    int t = threadIdx.x;
    int i = blockIdx.x * 256 + t;
    int v = (i < n) ? counts[i] : 0;
    sh[t] = v; __syncthreads();
    for (int off = 1; off < 256; off <<= 1) {
        int x = (t >= off) ? sh[t - off] : 0;
        __syncthreads();
        sh[t] += x; __syncthreads();
    }
    int excl = sh[t] - v + bsumx[blockIdx.x];
    if (i < n) {
        rowptr[i] = excl;
        wptr[i]   = excl;
        disq[i]   = rsqrtf((float)(v + 1));   // +1 self-loop
    }
    if (i == 0) rowptr[n] = e;
}

// ============ one-time: convert Wh[5] + jkW[6] to bf16, transposed [col][k] ============
__global__ void k_cvtw(const float* __restrict__ Wh, const float* __restrict__ jkW,
                       unsigned short* __restrict__ WtAll) {
    int i = blockIdx.x * 256 + threadIdx.x;     // 11*4096
    if (i >= 11 * 4096) return;
    int m = i >> 12;
    int r = (i >> 6) & 63;   // out col
    int c = i & 63;          // out k
    const float* srcm = (m < 5) ? (Wh + (size_t)m * 4096) : (jkW + (size_t)(m - 5) * 4096);
    WtAll[i] = f2bf(srcm[c * 64 + r]);          // transpose
}

// ============ fused: layer-0 GEMM (blocks FIRST) + XCD-partitioned scatter ============
__global__ __launch_bounds__(256) void k_scatter_gemm0(
    const int* __restrict__ src, const int* __restrict__ dst,
    int* __restrict__ wptr, int* __restrict__ csr, int e,
    const float* __restrict__ x, const float* __restrict__ W0,
    const float* __restrict__ disq, unsigned* __restrict__ C8, int n)
{
    __shared__ float Ws[32 * 64];    // 8KB
    __shared__ float As[64 * 36];    // 9.2KB

    if (blockIdx.x >= GEMM_GRID) {
        int sbid = blockIdx.x - GEMM_GRID;
        int part = sbid & 7;
        int i0 = (sbid >> 3) * 2048 + threadIdx.x;
        #pragma unroll
        for (int k = 0; k < 8; k++) {
            int i = i0 + k * 256;
            if (i < e) {
                int d = dst[i];
                if (d / PART_SZ == part) {
                    int pos = atomicAdd(&wptr[d], 1);
                    csr[pos] = src[i];
                }
            }
        }
        return;
    }

    const int tid  = threadIdx.x;
    const int col4 = (tid & 15) * 4;
    const int rowq = tid >> 4;
    const int base = blockIdx.x * 64;
    const int ar   = tid >> 3;
    const int ac4  = (tid & 7) * 4;

    float4 wreg[2], areg[2];
    #pragma unroll
    for (int i = 0; i < 2; i++)
        wreg[i] = *(const float4*)(W0 + (size_t)(i * 256 + tid) * 4);
    #pragma unroll
    for (int rr = 0; rr < 2; rr++) {
        int row = base + ar + rr * 32;
        areg[rr] = make_float4(0.f, 0.f, 0.f, 0.f);
        if (row < n) areg[rr] = *(const float4*)(x + (size_t)row * F_INF + ac4);
    }
    #pragma unroll
    for (int i = 0; i < 2; i++)
        *(float4*)(Ws + (size_t)(i * 256 + tid) * 4) = wreg[i];
    #pragma unroll
    for (int rr = 0; rr < 2; rr++)
        *(float4*)(As + (size_t)(ar + rr * 32) * 36 + ac4) = areg[rr];
    __syncthreads();

    float4 acc[4];
    #pragma unroll
    for (int r = 0; r < 4; r++) acc[r] = make_float4(0.f, 0.f, 0.f, 0.f);

    for (int k0 = 0; k0 < F_INF; k0 += 32) {
        const bool more = (k0 + 32) < F_INF;
        if (more) {
            #pragma unroll
            for (int i = 0; i < 2; i++)
                wreg[i] = *(const float4*)(W0 + (size_t)(k0 + 32) * 64 + (i * 256 + tid) * 4);
            #pragma unroll
            for (int rr = 0; rr < 2; rr++) {
                int row = base + ar + rr * 32;
                areg[rr] = make_float4(0.f, 0.f, 0.f, 0.f);
                if (row < n) areg[rr] = *(const float4*)(x + (size_t)row * F_INF + k0 + 32 + ac4);
            }
        }
        #pragma unroll 8
        for (int k = 0; k < 32; k++) {
            float4 w = *(const float4*)(Ws + k * 64 + col4);
            float a0 = As[(rowq * 4 + 0) * 36 + k];
            float a1 = As[(rowq * 4 + 1) * 36 + k];
            float a2 = As[(rowq * 4 + 2) * 36 + k];
            float a3 = As[(rowq * 4 + 3) * 36 + k];
            acc[0].x = fmaf(a0, w.x, acc[0].x); acc[0].y = fmaf(a0, w.y, acc[0].y);
            acc[0].z = fmaf(a0, w.z, acc[0].z); acc[0].w = fmaf(a0, w.w, acc[0].w);
            acc[1].x = fmaf(a1, w.x, acc[1].x); acc[1].y = fmaf(a1, w.y, acc[1].y);
            acc[1].z = fmaf(a1, w.z, acc[1].z); acc[1].w = fmaf(a1, w.w, acc[1].w);
            acc[2].x = fmaf(a2, w.x, acc[2].x); acc[2].y = fmaf(a2, w.y, acc[2].y);
            acc[2].z = fmaf(a2, w.z, acc[2].z); acc[2].w = fmaf(a2, w.w, acc[2].w);
            acc[3].x = fmaf(a3, w.x, acc[3].x); acc[3].y = fmaf(a3, w.y, acc[3].y);
            acc[3].z = fmaf(a3, w.z, acc[3].z); acc[3].w = fmaf(a3, w.w, acc[3].w);
        }
        __syncthreads();
        if (more) {
            #pragma unroll
            for (int i = 0; i < 2; i++)
                *(float4*)(Ws + (size_t)(i * 256 + tid) * 4) = wreg[i];
            #pragma unroll
            for (int rr = 0; rr < 2; rr++)
                *(float4*)(As + (size_t)(ar + rr * 32) * 36 + ac4) = areg[rr];
            __syncthreads();
        }
    }

    #pragma unroll
    for (int r = 0; r < 4; r++) {
        int row = base + rowq * 4 + r;
        if (row < n) {
            float s = disq[row];
            float4 o;
            o.x = acc[r].x * s; o.y = acc[r].y * s;
            o.z = acc[r].z * s; o.w = acc[r].w * s;
            C8[(size_t)row * 16 + (tid & 15)] = f4_fp8(o);
        }
    }
}

// ============ MFMA dual GEMM layers 1-5: A bf16 [n][64]; Wt/jkWt bf16 [col][k] ============
// wave w owns row-tile w (rows 16w..16w+15); 4 col-tiles each; 16 MFMA total.
// Fragment map: A lane: row=lane&15, k=8*(lane>>4)+j. B lane: col=lane&15, same k.
// C/D (verified m89): col=lane&15, row=4*(lane>>4)+reg.
__global__ __launch_bounds__(256) void k_gemm_dual_mfma(
    const unsigned short* __restrict__ Abf,
    const unsigned short* __restrict__ Wt,
    const unsigned short* __restrict__ jkWt,
    const float* __restrict__ disq,
    unsigned* __restrict__ C8,
    unsigned short* __restrict__ jkacc16,
    int jk_mode, int n)
{
    __shared__ float Cs[64 * 68];
    const int tid  = threadIdx.x;
    const int lane = tid & 63;
    const int wave = tid >> 6;
    const int base = blockIdx.x * 64;
    const int rtl  = lane & 15;
    const int kg   = lane >> 4;

    int arow = base + wave * 16 + rtl;
    bf16x8 a0 = {0, 0, 0, 0, 0, 0, 0, 0}, a1 = a0;
    if (arow < n) {
        a0 = *(const bf16x8*)(Abf + (size_t)arow * 64 + kg * 8);
        a1 = *(const bf16x8*)(Abf + (size_t)arow * 64 + 32 + kg * 8);
    }

    f32x4 acc[4], acc2[4];
    #pragma unroll
    for (int c = 0; c < 4; c++) {
        bf16x8 b0 = *(const bf16x8*)(Wt   + (size_t)(c * 16 + rtl) * 64 + kg * 8);
        bf16x8 b1 = *(const bf16x8*)(Wt   + (size_t)(c * 16 + rtl) * 64 + 32 + kg * 8);
        bf16x8 j0 = *(const bf16x8*)(jkWt + (size_t)(c * 16 + rtl) * 64 + kg * 8);
        bf16x8 j1 = *(const bf16x8*)(jkWt + (size_t)(c * 16 + rtl) * 64 + 32 + kg * 8);
        f32x4 z = {0.f, 0.f, 0.f, 0.f};
        acc[c]  = __builtin_amdgcn_mfma_f32_16x16x32_bf16(a0, b0, z, 0, 0, 0);
        acc[c]  = __builtin_amdgcn_mfma_f32_16x16x32_bf16(a1, b1, acc[c], 0, 0, 0);
        acc2[c] = __builtin_amdgcn_mfma_f32_16x16x32_bf16(a0, j0, z, 0, 0, 0);
        acc2[c] = __builtin_amdgcn_mfma_f32_16x16x32_bf16(a1, j1, acc2[c], 0, 0, 0);
    }

    // ---- stage acc -> LDS, epilogue 1 (fp8 C write) ----
    #pragma unroll
    for (int c = 0; c < 4; c++)
        #pragma unroll
        for (int r = 0; r < 4; r++)
            Cs[(wave * 16 + kg * 4 + r) * 68 + c * 16 + rtl] = acc[c][r];
    __syncthreads();

    const int rowq = tid >> 4;
    const int col4 = (tid & 15) * 4;
    #pragma unroll
    for (int r = 0; r < 4; r++) {
        int row = base + rowq * 4 + r;
        if (row < n) {
            float s = disq[row];
            float4 o;
            o.x = Cs[(rowq * 4 + r) * 68 + col4 + 0] * s;
            o.y = Cs[(rowq * 4 + r) * 68 + col4 + 1] * s;
            o.z = Cs[(rowq * 4 + r) * 68 + col4 + 2] * s;
            o.w = Cs[(rowq * 4 + r) * 68 + col4 + 3] * s;
            C8[(size_t)row * 16 + (tid & 15)] = f4_fp8(o);
        }
    }
    __syncthreads();

    // ---- stage acc2 -> LDS, epilogue 2 (jkacc16 fp16) ----
    #pragma unroll
    for (int c = 0; c < 4; c++)
        #pragma unroll
        for (int r = 0; r < 4; r++)
            Cs[(wave * 16 + kg * 4 + r) * 68 + c * 16 + rtl] = acc2[c][r];
    __syncthreads();

    #pragma unroll
    for (int r = 0; r < 4; r++) {
        int row = base + rowq * 4 + r;
        if (row < n) {
            float4 q;
            q.x = Cs[(rowq * 4 + r) * 68 + col4 + 0];
            q.y = Cs[(rowq * 4 + r) * 68 + col4 + 1];
            q.z = Cs[(rowq * 4 + r) * 68 + col4 + 2];
            q.w = Cs[(rowq * 4 + r) * 68 + col4 + 3];
            if (jk_mode == 1) {
                ((ushort4*)jkacc16)[(size_t)row * 16 + (tid & 15)] = f4h(q);
            } else {
                float4 p = h4f(((const ushort4*)jkacc16)[(size_t)row * 16 + (tid & 15)]);
                p.x += q.x; p.y += q.y; p.z += q.z; p.w += q.w;
                ((ushort4*)jkacc16)[(size_t)row * 16 + (tid & 15)] = f4h(p);
            }
        }
    }
}

// ============ gather: wave per node, fp8 in (64B row = 1 line/edge), bf16 out ============
__global__ __launch_bounds__(256) void k_gather(
    const int* __restrict__ rowptr, const int* __restrict__ csr,
    const unsigned* __restrict__ hW8, const float* __restrict__ disq,
    const float* __restrict__ bias, unsigned short* __restrict__ houtbf, int n)
{
    int wid  = (blockIdx.x * 256 + threadIdx.x) >> 6;
    if (wid >= n) return;
    int lane = threadIdx.x & 63;
    int fb = lane & 15;
    int es = lane >> 4;
    int j  = rowptr[wid];
    int r1 = rowptr[wid + 1];
    float4 v  = make_float4(0.f, 0.f, 0.f, 0.f);
    float4 v2 = make_float4(0.f, 0.f, 0.f, 0.f);
    if (es == 0) accf8(hW8[(size_t)wid * 16 + fb], v);   // self-loop
    while (j < r1) {
        int cnt = min(r1 - j, 64);
        int idx = (lane < cnt) ? csr[j + lane] : 0;
        for (int jj = 0; jj < cnt; jj += 16) {
            int i0 = jj + es, i1 = jj + 4 + es, i2 = jj + 8 + es, i3 = jj + 12 + es;
            int s0 = __shfl(idx, i0 & 63);
            int s1 = __shfl(idx, i1 & 63);
            int s2 = __shfl(idx, i2 & 63);
            int s3 = __shfl(idx, i3 & 63);
            unsigned t0 = hW8[(size_t)s0 * 16 + fb];
            unsigned t1 = hW8[(size_t)s1 * 16 + fb];
            unsigned t2 = hW8[(size_t)s2 * 16 + fb];
            unsigned t3 = hW8[(size_t)s3 * 16 + fb];
            if (i0 < cnt) accf8(t0, v);
            if (i1 < cnt) accf8(t1, v2);
            if (i2 < cnt) accf8(t2, v);
            if (i3 < cnt) accf8(t3, v2);
        }
        j += cnt;
    }
    v.x += v2.x; v.y += v2.y; v.z += v2.z; v.w += v2.w;
    v.x += __shfl_xor(v.x, 16); v.y += __shfl_xor(v.y, 16);
    v.z += __shfl_xor(v.z, 16); v.w += __shfl_xor(v.w, 16);
    v.x += __shfl_xor(v.x, 32); v.y += __shfl_xor(v.y, 32);
    v.z += __shfl_xor(v.z, 32); v.w += __shfl_xor(v.w, 32);
    if (es == 0) {
        float s = disq[wid];
        float4 b = ((const float4*)bias)[fb];
        float4 o;
        o.x = fmaxf(fmaf(s, v.x, b.x), 0.f);
        o.y = fmaxf(fmaf(s, v.y, b.y), 0.f);
        o.z = fmaxf(fmaf(s, v.z, b.z), 0.f);
        o.w = fmaxf(fmaf(s, v.w, b.w), 0.f);
        ((ushort4*)houtbf)[(size_t)wid * 16 + fb] = f4bf(o);
    }
}

// ============ final: t = relu(h@jkW5 + jkacc + jkb); pool by batch ============
__global__ __launch_bounds__(256) void k_jkfin_pool(
    const unsigned short* __restrict__ Abf,   // h [n][64] bf16
    const float* __restrict__ W,
    const unsigned short* __restrict__ jkacc16,
    const float* __restrict__ bias,
    const int* __restrict__ batch,
    float* __restrict__ pooled,
    int n)
{
    __shared__ float Ws[64 * 64];
    __shared__ float As[64 * 68];
    const int tid  = threadIdx.x;
    const int col4 = (tid & 15) * 4;
    const int rowq = tid >> 4;
    const int base = blockIdx.x * 64;

    #pragma unroll
    for (int i = 0; i < 4; i++) {
        float4 v = *(const float4*)(W + (size_t)(i * 256 + tid) * 4);
        *(float4*)(Ws + (size_t)(i * 256 + tid) * 4) = v;
    }
    {
        const ushort4* Ah = (const ushort4*)Abf;
        #pragma unroll
        for (int rr = 0; rr < 4; rr++) {
            int row = base + rowq + rr * 16;
            float4 v = make_float4(0.f, 0.f, 0.f, 0.f);
            if (row < n) v = bf4f(Ah[(size_t)row * 16 + (tid & 15)]);
            *(float4*)(As + (size_t)(rowq + rr * 16) * 68 + col4) = v;
        }
    }
    __syncthreads();

    float4 acc[4];
    #pragma unroll
    for (int r = 0; r < 4; r++) acc[r] = make_float4(0.f, 0.f, 0.f, 0.f);
    #pragma unroll 8
    for (int k = 0; k < 64; k++) {
        float4 w = *(const float4*)(Ws + k * 64 + col4);
        float a0 = As[(rowq * 4 + 0) * 68 + k];
        float a1 = As[(rowq * 4 + 1) * 68 + k];
        float a2 = As[(rowq * 4 + 2) * 68 + k];
        float a3 = As[(rowq * 4 + 3) * 68 + k];
        acc[0].x = fmaf(a0, w.x, acc[0].x); acc[0].y = fmaf(a0, w.y, acc[0].y);
        acc[0].z = fmaf(a0, w.z, acc[0].z); acc[0].w = fmaf(a0, w.w, acc[0].w);
        acc[1].x = fmaf(a1, w.x, acc[1].x); acc[1].y = fmaf(a1, w.y, acc[1].y);
        acc[1].z = fmaf(a1, w.z, acc[1].z); acc[1].w = fmaf(a1, w.w, acc[1].w);
        acc[2].x = fmaf(a2, w.x, acc[2].x); acc[2].y = fmaf(a2, w.y, acc[2].y);
        acc[2].z = fmaf(a2, w.z, acc[2].z); acc[2].w = fmaf(a2, w.w, acc[2].w);
        acc[3].x = fmaf(a3, w.x, acc[3].x); acc[3].y = fmaf(a3, w.y, acc[3].y);
        acc[3].z = fmaf(a3, w.z, acc[3].z); acc[3].w = fmaf(a3, w.w, acc[3].w);
    }
    __syncthreads();

    float* slab = Ws;
    #pragma unroll
    for (int i = tid; i < 4096; i += 256) slab[i] = 0.f;
    __syncthreads();

    float4 bb = *(const float4*)(bias + col4);
    int curg = -1;
    float4 s4 = make_float4(0.f, 0.f, 0.f, 0.f);
    #pragma unroll
    for (int r = 0; r < 4; r++) {
        int row = base + rowq * 4 + r;
        if (row < n) {
            float4 p = h4f(((const ushort4*)jkacc16)[(size_t)row * 16 + (tid & 15)]);
            float4 vv;
            vv.x = fmaxf(acc[r].x + p.x + bb.x, 0.f);
            vv.y = fmaxf(acc[r].y + p.y + bb.y, 0.f);
            vv.z = fmaxf(acc[r].z + p.z + bb.z, 0.f);
            vv.w = fmaxf(acc[r].w + p.w + bb.w, 0.f);
            int g = batch[row];
            if (g != curg) {
                if (curg >= 0) {
                    atomicAdd(&slab[curg * 64 + col4 + 0], s4.x);
                    atomicAdd(&slab[curg * 64 + col4 + 1], s4.y);
                    atomicAdd(&slab[curg * 64 + col4 + 2], s4.z);
                    atomicAdd(&slab[curg * 64 + col4 + 3], s4.w);
                }
                curg = g; s4 = vv;
            } else {
                s4.x += vv.x; s4.y += vv.y; s4.z += vv.z; s4.w += vv.w;
            }
        }
    }
    if (curg >= 0) {
        atomicAdd(&slab[curg * 64 + col4 + 0], s4.x);
        atomicAdd(&slab[curg * 64 + col4 + 1], s4.y);
        atomicAdd(&slab[curg * 64 + col4 + 2], s4.z);
        atomicAdd(&slab[curg * 64 + col4 + 3], s4.w);
    }
    __syncthreads();

    int g0 = batch[base];
    int g1 = batch[(base + 63 < n) ? (base + 63) : (n - 1)];
    int cnt = (g1 - g0 + 1) * 64;
    for (int i = tid; i < cnt; i += 256) {
        int g = g0 + (i >> 6);
        int c = i & 63;
        float v = slab[g * 64 + c];
        if (v != 0.f) atomicAdd(&pooled[g * 64 + c], v);
    }
}

// ============ head ============
__global__ __launch_bounds__(64) void k_head(
    const float* __restrict__ pooled,
    const float* __restrict__ W1, const float* __restrict__ b1,
    const float* __restrict__ W2, const float* __restrict__ b2,
    float* __restrict__ out)
{
    __shared__ float p[64];
    __shared__ float h1[64];
    __shared__ float lg[16];
    const int g = blockIdx.x;
    const int t = threadIdx.x;

    p[t] = pooled[g * 64 + t];
    __syncthreads();

    float acc = b1[t];
    #pragma unroll 8
    for (int k = 0; k < 64; k++) acc = fmaf(p[k], W1[k * 64 + t], acc);
    h1[t] = fmaxf(acc, 0.f);
    __syncthreads();

    if (t < NCLS) {
        float a = b2[t];
        #pragma unroll 8
        for (int j = 0; j < 64; j++) a = fmaf(h1[j], W2[j * NCLS + t], a);
        lg[t] = a;
    }
    __syncthreads();

    if (t == 0) {
        float mx = lg[0];
        #pragma unroll
        for (int c = 1; c < NCLS; c++) mx = fmaxf(mx, lg[c]);
        float ssum = 0.f;
        float e[NCLS];
        #pragma unroll
        for (int c = 0; c < NCLS; c++) { e[c] = __expf(lg[c] - mx); ssum += e[c]; }
        float inv = 1.0f / ssum;
        #pragma unroll
        for (int c = 0; c < NCLS; c++) out[g * NCLS + c] = e[c] * inv;
    }
}

extern "C" void kernel_launch(void* const* d_in, const int* in_sizes, int n_in,
                              void* d_out, int out_size, void* d_ws, size_t ws_size,
                              hipStream_t stream) {
    (void)in_sizes; (void)n_in; (void)out_size; (void)ws_size;
    const float* x     = (const float*)d_in[0];
    const int*   ei    = (const int*)d_in[1];
    const int*   batch = (const int*)d_in[2];
    const float* W0    = (const float*)d_in[3];
    const float* b0    = (const float*)d_in[4];
    const float* Wh    = (const float*)d_in[5];
    const float* bh    = (const float*)d_in[6];
    const float* jkW   = (const float*)d_in[7];
    const float* jkb   = (const float*)d_in[8];
    const float* W1    = (const float*)d_in[9];
    const float* b1    = (const float*)d_in[10];
    const float* W2    = (const float*)d_in[11];
    const float* b2    = (const float*)d_in[12];

    const int* src = ei;
    const int* dst = ei + NE;

    float*          fws     = (float*)d_ws;
    float*          disq    = fws;                                   // 100352 f
    unsigned*       hWb8    = (unsigned*)(disq + 100352);            // NN*16 u32 (fp8 rows)
    unsigned short* hbf     = (unsigned short*)(hWb8 + (size_t)NN * 16);  // NN*64 bf16
    unsigned short* jkacc16 = hbf + (size_t)NN * 64;                 // NN*64 fp16
    float*          pooled  = (float*)(jkacc16 + (size_t)NN * 64);   // 4096 f
    int*            counts  = (int*)(pooled + 4096);
    int*            rowptr  = counts + 100352;
    int*            wptr    = rowptr + 100352;
    int*            bsum    = wptr + 100352;
    int*            csr     = bsum + 512;                            // NE
    unsigned short* wtbf    = (unsigned short*)(csr + NE);           // 11*4096 bf16

    const int NB_N = (NN + 255) / 256;

    k_cvtw<<<(11 * 4096 + 255) / 256, 256, 0, stream>>>(Wh, jkW, wtbf);

    hipMemsetAsync(counts, 0, (size_t)NN * sizeof(int), stream);
    k_hist<<<(NE + 1023) / 1024, 256, 0, stream>>>(dst, counts, NE);
    k_blocksum<<<NB_N, 256, 0, stream>>>(counts, bsum, NN);
    k_scanbsum<<<1, 512, 0, stream>>>(bsum, NB_N);
    k_scanwrite<<<NB_N, 256, 0, stream>>>(counts, bsum, rowptr, wptr, disq, NN, NE);

    // fused: GEMM blocks first, scatter behind
    k_scatter_gemm0<<<GEMM_GRID + SCAT_BLKS, 256, 0, stream>>>(
        src, dst, wptr, csr, NE, x, W0, disq, hWb8, NN);

    const int gather_grid = (NN + 3) / 4;
    k_gather<<<gather_grid, 256, 0, stream>>>(rowptr, csr, hWb8, disq, b0, hbf, NN);
    for (int l = 1; l < NLAY; l++) {
        const unsigned short* Wt  = wtbf + (size_t)(l - 1) * 4096;
        const unsigned short* jwt = wtbf + (size_t)(5 + l - 1) * 4096;
        int jkm = (l == 1) ? 1 : 2;
        k_gemm_dual_mfma<<<GEMM_GRID, 256, 0, stream>>>(hbf, Wt, jwt, disq,
                                                        hWb8, jkacc16, jkm, NN);
        k_gather<<<gather_grid, 256, 0, stream>>>(rowptr, csr, hWb8, disq,
                                                  bh + (size_t)(l - 1) * 64, hbf, NN);
    }

    hipMemsetAsync(pooled, 0, 64 * 64 * sizeof(float), stream);
    k_jkfin_pool<<<GEMM_GRID, 256, 0, stream>>>(hbf, jkW + (size_t)5 * 64 * 64, jkacc16,
                                                jkb, batch, pooled, NN);
    k_head<<<NGRAPH, 64, 0, stream>>>(pooled, W1, b1, W2, b2, (float*)d_out);
}

// Round 18
// 450.856 us; speedup vs baseline: 1.7271x; 1.0209x over previous
//
#include <hip/hip_runtime.h>
#include <hip/hip_fp16.h>

#define NN 100000
#define NE 1000000
#define F_INF 128
#define HID 64
#define NLAY 6
#define NCLS 10
#define NGRAPH 64
#define PART_SZ 12500   // NN/8 — contiguous node range per XCD partition
#define SCAT_BLKS (((NE + 2047) / 2048) * 8)   // 489*8 = 3912
#define GEMM_GRID ((NN + 63) / 64)             // 1563

typedef float floatx2 __attribute__((ext_vector_type(2)));
typedef short bf16x8 __attribute__((ext_vector_type(8)));
typedef float f32x4 __attribute__((ext_vector_type(4)));

__device__ __forceinline__ float4 h4f(ushort4 u) {
    __half2 lo = *reinterpret_cast<__half2*>(&u);
    __half2 hi = *reinterpret_cast<__half2*>(reinterpret_cast<unsigned short*>(&u) + 2);
    float2 a = __half22float2(lo);
    float2 b = __half22float2(hi);
    return make_float4(a.x, a.y, b.x, b.y);
}

__device__ __forceinline__ ushort4 f4h(float4 v) {
    __half2 lo = __floats2half2_rn(v.x, v.y);
    __half2 hi = __floats2half2_rn(v.z, v.w);
    ushort4 u;
    *reinterpret_cast<__half2*>(&u) = lo;
    *reinterpret_cast<__half2*>(reinterpret_cast<unsigned short*>(&u) + 2) = hi;
    return u;
}

// ---- bf16 helpers (RNE) ----
__device__ __forceinline__ unsigned short f2bf(float f) {
    unsigned u = __float_as_uint(f);
    u += 0x7FFF + ((u >> 16) & 1);
    return (unsigned short)(u >> 16);
}
__device__ __forceinline__ float bf2f(unsigned short h) {
    return __uint_as_float(((unsigned)h) << 16);
}
__device__ __forceinline__ ushort4 f4bf(float4 v) {
    ushort4 u;
    u.x = f2bf(v.x); u.y = f2bf(v.y); u.z = f2bf(v.z); u.w = f2bf(v.w);
    return u;
}
__device__ __forceinline__ float4 bf4f(ushort4 u) {
    return make_float4(bf2f(u.x), bf2f(u.y), bf2f(u.z), bf2f(u.w));
}
__device__ __forceinline__ bf16x8 pack_bf8(float4 a, float4 b) {
    bf16x8 r;
    r[0] = (short)f2bf(a.x); r[1] = (short)f2bf(a.y);
    r[2] = (short)f2bf(a.z); r[3] = (short)f2bf(a.w);
    r[4] = (short)f2bf(b.x); r[5] = (short)f2bf(b.y);
    r[6] = (short)f2bf(b.z); r[7] = (short)f2bf(b.w);
    return r;
}

// fp8 (e4m3 ocp on gfx950) pack/unpack — roundtrip through our own buffers only
__device__ __forceinline__ unsigned f4_fp8(float4 v) {
    unsigned w = 0;
    w = __builtin_amdgcn_cvt_pk_fp8_f32(v.x, v.y, w, false);
    w = __builtin_amdgcn_cvt_pk_fp8_f32(v.z, v.w, w, true);
    return w;
}
__device__ __forceinline__ void accf8(unsigned u, float4& a) {
    floatx2 lo = __builtin_amdgcn_cvt_pk_f32_fp8(u, false);
    floatx2 hi = __builtin_amdgcn_cvt_pk_f32_fp8(u, true);
    a.x += lo[0]; a.y += lo[1]; a.z += hi[0]; a.w += hi[1];
}

// ================= CSR build =================
__global__ void k_hist(const int* __restrict__ dst, int* __restrict__ counts, int e) {
    int i0 = blockIdx.x * 1024 + threadIdx.x;
    #pragma unroll
    for (int k = 0; k < 4; k++) {
        int i = i0 + k * 256;
        if (i < e) atomicAdd(&counts[dst[i]], 1);
    }
}

__global__ void k_blocksum(const int* __restrict__ counts, int* __restrict__ bsum, int n) {
    int i = blockIdx.x * 256 + threadIdx.x;
    int v = (i < n) ? counts[i] : 0;
    #pragma unroll
    for (int off = 32; off >= 1; off >>= 1) v += __shfl_down(v, off);
    __shared__ int ws[4];
    if ((threadIdx.x & 63) == 0) ws[threadIdx.x >> 6] = v;
    __syncthreads();
    if (threadIdx.x == 0) bsum[blockIdx.x] = ws[0] + ws[1] + ws[2] + ws[3];
}

__global__ void k_scanbsum(int* __restrict__ bsum, int nb) {   // 1 block, 512 thr
    __shared__ int sh[512];
    int t = threadIdx.x;
    int v = (t < nb) ? bsum[t] : 0;
    sh[t] = v; __syncthreads();
    for (int off = 1; off < 512; off <<= 1) {
        int x = (t >= off) ? sh[t - off] : 0;
        __syncthreads();
        sh[t] += x; __syncthreads();
    }
    if (t < nb) bsum[t] = sh[t] - v;   // exclusive
}

__global__ void k_scanwrite(const int* __restrict__ counts, const int* __restrict__ bsumx,
                            int* __restrict__ rowptr, int* __restrict__ wptr,
                            float* __restrict__ disq, int n, int e) {
    __shared__ int sh[256];
    int t = threadIdx.x;
    int i = blockIdx.x * 256 + t;
    int v = (i < n) ? counts[i] : 0;
    sh[t] = v; __syncthreads();
    for (int off = 1; off < 256; off <<= 1) {
        int x = (t >= off) ? sh[t - off] : 0;
        __syncthreads();
        sh[t] += x; __syncthreads();
    }
    int excl = sh[t] - v + bsumx[blockIdx.x];
    if (i < n) {
        rowptr[i] = excl;
        wptr[i]   = excl;
        disq[i]   = rsqrtf((float)(v + 1));   // +1 self-loop
    }
    if (i == 0) rowptr[n] = e;
}

// ============ one-time: Wh[5] + jkW[6] -> bf16 transposed [col][64] ============
__global__ void k_cvtw(const float* __restrict__ Wh, const float* __restrict__ jkW,
                       unsigned short* __restrict__ WtAll) {
    int i = blockIdx.x * 256 + threadIdx.x;     // 11*4096
    if (i >= 11 * 4096) return;
    int m = i >> 12;
    int r = (i >> 6) & 63;   // out col
    int c = i & 63;          // out k
    const float* srcm = (m < 5) ? (Wh + (size_t)m * 4096) : (jkW + (size_t)(m - 5) * 4096);
    WtAll[i] = f2bf(srcm[c * 64 + r]);          // transpose
}

// ============ one-time: W0 [128][64] -> bf16 transposed [64][128] ============
__global__ void k_cvtw0(const float* __restrict__ W0, unsigned short* __restrict__ Wt0) {
    int i = blockIdx.x * 256 + threadIdx.x;     // 8192
    if (i >= 64 * 128) return;
    int r = i >> 7;          // out col 0..63
    int c = i & 127;         // out k 0..127
    Wt0[i] = f2bf(W0[c * 64 + r]);
}

// ============ fused: layer-0 MFMA GEMM (blocks FIRST) + XCD-partitioned scatter ============
// GEMM: A = x fp32 [n][128] converted in-kernel to bf16 fragments; B = Wt0 bf16 [64][128].
__global__ __launch_bounds__(256) void k_scatter_gemm0(
    const int* __restrict__ src, const int* __restrict__ dst,
    int* __restrict__ wptr, int* __restrict__ csr, int e,
    const float* __restrict__ x, const unsigned short* __restrict__ Wt0,
    const float* __restrict__ disq, unsigned* __restrict__ C8, int n)
{
    __shared__ float Cs[64 * 68];    // 17408 B — same footprint as R17

    if (blockIdx.x >= GEMM_GRID) {
        int sbid = blockIdx.x - GEMM_GRID;
        int part = sbid & 7;
        int i0 = (sbid >> 3) * 2048 + threadIdx.x;
        #pragma unroll
        for (int k = 0; k < 8; k++) {
            int i = i0 + k * 256;
            if (i < e) {
                int d = dst[i];
                if (d / PART_SZ == part) {
                    int pos = atomicAdd(&wptr[d], 1);
                    csr[pos] = src[i];
                }
            }
        }
        return;
    }

    const int tid  = threadIdx.x;
    const int lane = tid & 63;
    const int wave = tid >> 6;
    const int base = blockIdx.x * 64;
    const int rtl  = lane & 15;
    const int kg   = lane >> 4;

    // A fragments: 4 K-chunks, converted fp32->bf16 (row=base+wave*16+rtl, k=kk*32+kg*8+j)
    int arow = base + wave * 16 + rtl;
    bf16x8 a[4];
    #pragma unroll
    for (int kk = 0; kk < 4; kk++) {
        float4 f0 = make_float4(0.f, 0.f, 0.f, 0.f), f1 = f0;
        if (arow < n) {
            f0 = *(const float4*)(x + (size_t)arow * F_INF + kk * 32 + kg * 8);
            f1 = *(const float4*)(x + (size_t)arow * F_INF + kk * 32 + kg * 8 + 4);
        }
        a[kk] = pack_bf8(f0, f1);
    }

    f32x4 acc[4];
    #pragma unroll
    for (int c = 0; c < 4; c++) {
        f32x4 z = {0.f, 0.f, 0.f, 0.f};
        acc[c] = z;
        #pragma unroll
        for (int kk = 0; kk < 4; kk++) {
            bf16x8 b = *(const bf16x8*)(Wt0 + (size_t)(c * 16 + rtl) * 128 + kk * 32 + kg * 8);
            acc[c] = __builtin_amdgcn_mfma_f32_16x16x32_bf16(a[kk], b, acc[c], 0, 0, 0);
        }
    }

    // stage -> LDS, fp8 epilogue (C/D map: col=lane&15, row=4*(lane>>4)+reg)
    #pragma unroll
    for (int c = 0; c < 4; c++)
        #pragma unroll
        for (int r = 0; r < 4; r++)
            Cs[(wave * 16 + kg * 4 + r) * 68 + c * 16 + rtl] = acc[c][r];
    __syncthreads();

    const int rowq = tid >> 4;
    const int col4 = (tid & 15) * 4;
    #pragma unroll
    for (int r = 0; r < 4; r++) {
        int row = base + rowq * 4 + r;
        if (row < n) {
            float s = disq[row];
            float4 o;
            o.x = Cs[(rowq * 4 + r) * 68 + col4 + 0] * s;
            o.y = Cs[(rowq * 4 + r) * 68 + col4 + 1] * s;
            o.z = Cs[(rowq * 4 + r) * 68 + col4 + 2] * s;
            o.w = Cs[(rowq * 4 + r) * 68 + col4 + 3] * s;
            C8[(size_t)row * 16 + (tid & 15)] = f4_fp8(o);
        }
    }
}

// ============ MFMA dual GEMM layers 1-5 (R17-verified) ============
__global__ __launch_bounds__(256) void k_gemm_dual_mfma(
    const unsigned short* __restrict__ Abf,
    const unsigned short* __restrict__ Wt,
    const unsigned short* __restrict__ jkWt,
    const float* __restrict__ disq,
    unsigned* __restrict__ C8,
    unsigned short* __restrict__ jkacc16,
    int jk_mode, int n)
{
    __shared__ float Cs[64 * 68];
    const int tid  = threadIdx.x;
    const int lane = tid & 63;
    const int wave = tid >> 6;
    const int base = blockIdx.x * 64;
    const int rtl  = lane & 15;
    const int kg   = lane >> 4;

    int arow = base + wave * 16 + rtl;
    bf16x8 a0 = {0, 0, 0, 0, 0, 0, 0, 0}, a1 = a0;
    if (arow < n) {
        a0 = *(const bf16x8*)(Abf + (size_t)arow * 64 + kg * 8);
        a1 = *(const bf16x8*)(Abf + (size_t)arow * 64 + 32 + kg * 8);
    }

    f32x4 acc[4], acc2[4];
    #pragma unroll
    for (int c = 0; c < 4; c++) {
        bf16x8 b0 = *(const bf16x8*)(Wt   + (size_t)(c * 16 + rtl) * 64 + kg * 8);
        bf16x8 b1 = *(const bf16x8*)(Wt   + (size_t)(c * 16 + rtl) * 64 + 32 + kg * 8);
        bf16x8 j0 = *(const bf16x8*)(jkWt + (size_t)(c * 16 + rtl) * 64 + kg * 8);
        bf16x8 j1 = *(const bf16x8*)(jkWt + (size_t)(c * 16 + rtl) * 64 + 32 + kg * 8);
        f32x4 z = {0.f, 0.f, 0.f, 0.f};
        acc[c]  = __builtin_amdgcn_mfma_f32_16x16x32_bf16(a0, b0, z, 0, 0, 0);
        acc[c]  = __builtin_amdgcn_mfma_f32_16x16x32_bf16(a1, b1, acc[c], 0, 0, 0);
        acc2[c] = __builtin_amdgcn_mfma_f32_16x16x32_bf16(a0, j0, z, 0, 0, 0);
        acc2[c] = __builtin_amdgcn_mfma_f32_16x16x32_bf16(a1, j1, acc2[c], 0, 0, 0);
    }

    #pragma unroll
    for (int c = 0; c < 4; c++)
        #pragma unroll
        for (int r = 0; r < 4; r++)
            Cs[(wave * 16 + kg * 4 + r) * 68 + c * 16 + rtl] = acc[c][r];
    __syncthreads();

    const int rowq = tid >> 4;
    const int col4 = (tid & 15) * 4;
    #pragma unroll
    for (int r = 0; r < 4; r++) {
        int row = base + rowq * 4 + r;
        if (row < n) {
            float s = disq[row];
            float4 o;
            o.x = Cs[(rowq * 4 + r) * 68 + col4 + 0] * s;
            o.y = Cs[(rowq * 4 + r) * 68 + col4 + 1] * s;
            o.z = Cs[(rowq * 4 + r) * 68 + col4 + 2] * s;
            o.w = Cs[(rowq * 4 + r) * 68 + col4 + 3] * s;
            C8[(size_t)row * 16 + (tid & 15)] = f4_fp8(o);
        }
    }
    __syncthreads();

    #pragma unroll
    for (int c = 0; c < 4; c++)
        #pragma unroll
        for (int r = 0; r < 4; r++)
            Cs[(wave * 16 + kg * 4 + r) * 68 + c * 16 + rtl] = acc2[c][r];
    __syncthreads();

    #pragma unroll
    for (int r = 0; r < 4; r++) {
        int row = base + rowq * 4 + r;
        if (row < n) {
            float4 q;
            q.x = Cs[(rowq * 4 + r) * 68 + col4 + 0];
            q.y = Cs[(rowq * 4 + r) * 68 + col4 + 1];
            q.z = Cs[(rowq * 4 + r) * 68 + col4 + 2];
            q.w = Cs[(rowq * 4 + r) * 68 + col4 + 3];
            if (jk_mode == 1) {
                ((ushort4*)jkacc16)[(size_t)row * 16 + (tid & 15)] = f4h(q);
            } else {
                float4 p = h4f(((const ushort4*)jkacc16)[(size_t)row * 16 + (tid & 15)]);
                p.x += q.x; p.y += q.y; p.z += q.z; p.w += q.w;
                ((ushort4*)jkacc16)[(size_t)row * 16 + (tid & 15)] = f4h(p);
            }
        }
    }
}

// ============ gather: wave per node, fp8 in (64B row = 1 line/edge), bf16 out ============
__global__ __launch_bounds__(256) void k_gather(
    const int* __restrict__ rowptr, const int* __restrict__ csr,
    const unsigned* __restrict__ hW8, const float* __restrict__ disq,
    const float* __restrict__ bias, unsigned short* __restrict__ houtbf, int n)
{
    int wid  = (blockIdx.x * 256 + threadIdx.x) >> 6;
    if (wid >= n) return;
    int lane = threadIdx.x & 63;
    int fb = lane & 15;
    int es = lane >> 4;
    int j  = rowptr[wid];
    int r1 = rowptr[wid + 1];
    float4 v  = make_float4(0.f, 0.f, 0.f, 0.f);
    float4 v2 = make_float4(0.f, 0.f, 0.f, 0.f);
    if (es == 0) accf8(hW8[(size_t)wid * 16 + fb], v);   // self-loop
    while (j < r1) {
        int cnt = min(r1 - j, 64);
        int idx = (lane < cnt) ? csr[j + lane] : 0;
        for (int jj = 0; jj < cnt; jj += 16) {
            int i0 = jj + es, i1 = jj + 4 + es, i2 = jj + 8 + es, i3 = jj + 12 + es;
            int s0 = __shfl(idx, i0 & 63);
            int s1 = __shfl(idx, i1 & 63);
            int s2 = __shfl(idx, i2 & 63);
            int s3 = __shfl(idx, i3 & 63);
            unsigned t0 = hW8[(size_t)s0 * 16 + fb];
            unsigned t1 = hW8[(size_t)s1 * 16 + fb];
            unsigned t2 = hW8[(size_t)s2 * 16 + fb];
            unsigned t3 = hW8[(size_t)s3 * 16 + fb];
            if (i0 < cnt) accf8(t0, v);
            if (i1 < cnt) accf8(t1, v2);
            if (i2 < cnt) accf8(t2, v);
            if (i3 < cnt) accf8(t3, v2);
        }
        j += cnt;
    }
    v.x += v2.x; v.y += v2.y; v.z += v2.z; v.w += v2.w;
    v.x += __shfl_xor(v.x, 16); v.y += __shfl_xor(v.y, 16);
    v.z += __shfl_xor(v.z, 16); v.w += __shfl_xor(v.w, 16);
    v.x += __shfl_xor(v.x, 32); v.y += __shfl_xor(v.y, 32);
    v.z += __shfl_xor(v.z, 32); v.w += __shfl_xor(v.w, 32);
    if (es == 0) {
        float s = disq[wid];
        float4 b = ((const float4*)bias)[fb];
        float4 o;
        o.x = fmaxf(fmaf(s, v.x, b.x), 0.f);
        o.y = fmaxf(fmaf(s, v.y, b.y), 0.f);
        o.z = fmaxf(fmaf(s, v.z, b.z), 0.f);
        o.w = fmaxf(fmaf(s, v.w, b.w), 0.f);
        ((ushort4*)houtbf)[(size_t)wid * 16 + fb] = f4bf(o);
    }
}

// ============ final: MFMA t = h@jkW5; relu(t + jkacc + jkb); pool by batch ============
__global__ __launch_bounds__(256) void k_jkfin_pool(
    const unsigned short* __restrict__ Abf,   // h [n][64] bf16
    const unsigned short* __restrict__ jkWt5, // jkW[5] transposed bf16 [col][64]
    const unsigned short* __restrict__ jkacc16,
    const float* __restrict__ bias,
    const int* __restrict__ batch,
    float* __restrict__ pooled,
    int n)
{
    __shared__ float Cs[64 * 68];
    __shared__ float slab[4096];
    const int tid  = threadIdx.x;
    const int lane = tid & 63;
    const int wave = tid >> 6;
    const int base = blockIdx.x * 64;
    const int rtl  = lane & 15;
    const int kg   = lane >> 4;

    int arow = base + wave * 16 + rtl;
    bf16x8 a0 = {0, 0, 0, 0, 0, 0, 0, 0}, a1 = a0;
    if (arow < n) {
        a0 = *(const bf16x8*)(Abf + (size_t)arow * 64 + kg * 8);
        a1 = *(const bf16x8*)(Abf + (size_t)arow * 64 + 32 + kg * 8);
    }

    f32x4 acc[4];
    #pragma unroll
    for (int c = 0; c < 4; c++) {
        bf16x8 b0 = *(const bf16x8*)(jkWt5 + (size_t)(c * 16 + rtl) * 64 + kg * 8);
        bf16x8 b1 = *(const bf16x8*)(jkWt5 + (size_t)(c * 16 + rtl) * 64 + 32 + kg * 8);
        f32x4 z = {0.f, 0.f, 0.f, 0.f};
        acc[c] = __builtin_amdgcn_mfma_f32_16x16x32_bf16(a0, b0, z, 0, 0, 0);
        acc[c] = __builtin_amdgcn_mfma_f32_16x16x32_bf16(a1, b1, acc[c], 0, 0, 0);
    }

    #pragma unroll
    for (int c = 0; c < 4; c++)
        #pragma unroll
        for (int r = 0; r < 4; r++)
            Cs[(wave * 16 + kg * 4 + r) * 68 + c * 16 + rtl] = acc[c][r];

    #pragma unroll
    for (int i = tid; i < 4096; i += 256) slab[i] = 0.f;
    __syncthreads();

    const int rowq = tid >> 4;
    const int col4 = (tid & 15) * 4;
    float4 bb = *(const float4*)(bias + col4);
    int curg = -1;
    float4 s4 = make_float4(0.f, 0.f, 0.f, 0.f);
    #pragma unroll
    for (int r = 0; r < 4; r++) {
        int row = base + rowq * 4 + r;
        if (row < n) {
            float4 p = h4f(((const ushort4*)jkacc16)[(size_t)row * 16 + (tid & 15)]);
            float4 vv;
            vv.x = fmaxf(Cs[(rowq * 4 + r) * 68 + col4 + 0] + p.x + bb.x, 0.f);
            vv.y = fmaxf(Cs[(rowq * 4 + r) * 68 + col4 + 1] + p.y + bb.y, 0.f);
            vv.z = fmaxf(Cs[(rowq * 4 + r) * 68 + col4 + 2] + p.z + bb.z, 0.f);
            vv.w = fmaxf(Cs[(rowq * 4 + r) * 68 + col4 + 3] + p.w + bb.w, 0.f);
            int g = batch[row];
            if (g != curg) {
                if (curg >= 0) {
                    atomicAdd(&slab[curg * 64 + col4 + 0], s4.x);
                    atomicAdd(&slab[curg * 64 + col4 + 1], s4.y);
                    atomicAdd(&slab[curg * 64 + col4 + 2], s4.z);
                    atomicAdd(&slab[curg * 64 + col4 + 3], s4.w);
                }
                curg = g; s4 = vv;
            } else {
                s4.x += vv.x; s4.y += vv.y; s4.z += vv.z; s4.w += vv.w;
            }
        }
    }
    if (curg >= 0) {
        atomicAdd(&slab[curg * 64 + col4 + 0], s4.x);
        atomicAdd(&slab[curg * 64 + col4 + 1], s4.y);
        atomicAdd(&slab[curg * 64 + col4 + 2], s4.z);
        atomicAdd(&slab[curg * 64 + col4 + 3], s4.w);
    }
    __syncthreads();

    int g0 = batch[base];
    int g1 = batch[(base + 63 < n) ? (base + 63) : (n - 1)];
    int cnt = (g1 - g0 + 1) * 64;
    for (int i = tid; i < cnt; i += 256) {
        int g = g0 + (i >> 6);
        int c = i & 63;
        float v = slab[g * 64 + c];
        if (v != 0.f) atomicAdd(&pooled[g * 64 + c], v);
    }
}

// ============ head ============
__global__ __launch_bounds__(64) void k_head(
    const float* __restrict__ pooled,
    const float* __restrict__ W1, const float* __restrict__ b1,
    const float* __restrict__ W2, const float* __restrict__ b2,
    float* __restrict__ out)
{
    __shared__ float p[64];
    __shared__ float h1[64];
    __shared__ float lg[16];
    const int g = blockIdx.x;
    const int t = threadIdx.x;

    p[t] = pooled[g * 64 + t];
    __syncthreads();

    float acc = b1[t];
    #pragma unroll 8
    for (int k = 0; k < 64; k++) acc = fmaf(p[k], W1[k * 64 + t], acc);
    h1[t] = fmaxf(acc, 0.f);
    __syncthreads();

    if (t < NCLS) {
        float a = b2[t];
        #pragma unroll 8
        for (int j = 0; j < 64; j++) a = fmaf(h1[j], W2[j * NCLS + t], a);
        lg[t] = a;
    }
    __syncthreads();

    if (t == 0) {
        float mx = lg[0];
        #pragma unroll
        for (int c = 1; c < NCLS; c++) mx = fmaxf(mx, lg[c]);
        float ssum = 0.f;
        float e[NCLS];
        #pragma unroll
        for (int c = 0; c < NCLS; c++) { e[c] = __expf(lg[c] - mx); ssum += e[c]; }
        float inv = 1.0f / ssum;
        #pragma unroll
        for (int c = 0; c < NCLS; c++) out[g * NCLS + c] = e[c] * inv;
    }
}

extern "C" void kernel_launch(void* const* d_in, const int* in_sizes, int n_in,
                              void* d_out, int out_size, void* d_ws, size_t ws_size,
                              hipStream_t stream) {
    (void)in_sizes; (void)n_in; (void)out_size; (void)ws_size;
    const float* x     = (const float*)d_in[0];
    const int*   ei    = (const int*)d_in[1];
    const int*   batch = (const int*)d_in[2];
    const float* W0    = (const float*)d_in[3];
    const float* b0    = (const float*)d_in[4];
    const float* Wh    = (const float*)d_in[5];
    const float* bh    = (const float*)d_in[6];
    const float* jkW   = (const float*)d_in[7];
    const float* jkb   = (const float*)d_in[8];
    const float* W1    = (const float*)d_in[9];
    const float* b1    = (const float*)d_in[10];
    const float* W2    = (const float*)d_in[11];
    const float* b2    = (const float*)d_in[12];

    const int* src = ei;
    const int* dst = ei + NE;

    float*          fws     = (float*)d_ws;
    float*          disq    = fws;                                   // 100352 f
    unsigned*       hWb8    = (unsigned*)(disq + 100352);            // NN*16 u32 (fp8 rows)
    unsigned short* hbf     = (unsigned short*)(hWb8 + (size_t)NN * 16);  // NN*64 bf16
    unsigned short* jkacc16 = hbf + (size_t)NN * 64;                 // NN*64 fp16
    float*          pooled  = (float*)(jkacc16 + (size_t)NN * 64);   // 4096 f
    int*            counts  = (int*)(pooled + 4096);
    int*            rowptr  = counts + 100352;
    int*            wptr    = rowptr + 100352;
    int*            bsum    = wptr + 100352;
    int*            csr     = bsum + 512;                            // NE
    unsigned short* wtbf    = (unsigned short*)(csr + NE);           // 11*4096 bf16
    unsigned short* wt0bf   = wtbf + 11 * 4096;                      // 64*128 bf16

    const int NB_N = (NN + 255) / 256;

    k_cvtw<<<(11 * 4096 + 255) / 256, 256, 0, stream>>>(Wh, jkW, wtbf);
    k_cvtw0<<<(64 * 128 + 255) / 256, 256, 0, stream>>>(W0, wt0bf);

    hipMemsetAsync(counts, 0, (size_t)NN * sizeof(int), stream);
    k_hist<<<(NE + 1023) / 1024, 256, 0, stream>>>(dst, counts, NE);
    k_blocksum<<<NB_N, 256, 0, stream>>>(counts, bsum, NN);
    k_scanbsum<<<1, 512, 0, stream>>>(bsum, NB_N);
    k_scanwrite<<<NB_N, 256, 0, stream>>>(counts, bsum, rowptr, wptr, disq, NN, NE);

    // fused: MFMA GEMM blocks first, scatter behind
    k_scatter_gemm0<<<GEMM_GRID + SCAT_BLKS, 256, 0, stream>>>(
        src, dst, wptr, csr, NE, x, wt0bf, disq, hWb8, NN);

    const int gather_grid = (NN + 3) / 4;
    k_gather<<<gather_grid, 256, 0, stream>>>(rowptr, csr, hWb8, disq, b0, hbf, NN);
    for (int l = 1; l < NLAY; l++) {
        const unsigned short* Wt  = wtbf + (size_t)(l - 1) * 4096;
        const unsigned short* jwt = wtbf + (size_t)(5 + l - 1) * 4096;
        int jkm = (l == 1) ? 1 : 2;
        k_gemm_dual_mfma<<<GEMM_GRID, 256, 0, stream>>>(hbf, Wt, jwt, disq,
                                                        hWb8, jkacc16, jkm, NN);
        k_gather<<<gather_grid, 256, 0, stream>>>(rowptr, csr, hWb8, disq,
                                                  bh + (size_t)(l - 1) * 64, hbf, NN);
    }

    hipMemsetAsync(pooled, 0, 64 * 64 * sizeof(float), stream);
    k_jkfin_pool<<<GEMM_GRID, 256, 0, stream>>>(hbf, wtbf + (size_t)10 * 4096, jkacc16,
                                                jkb, batch, pooled, NN);
    k_head<<<NGRAPH, 64, 0, stream>>>(pooled, W1, b1, W2, b2, (float*)d_out);
}